// Round 5
// baseline (1251.769 us; speedup 1.0000x reference)
//
#include <hip/hip_runtime.h>
#include <hip/hip_bf16.h>

#define DEV __device__ __forceinline__

typedef __attribute__((ext_vector_type(8))) short s16x8;
typedef __attribute__((ext_vector_type(4))) float f32x4;

#define B_ 64
#define P_ 96
#define N_ 12
#define D_ 2048
#define W_ 85
#define M1_ (B_ * P_)   // 6144 rows stage-1
#define M2_ (B_ * W_)   // 5440 rows stage-2
#define M2P_ 5504       // padded to 43*128
#define SCALE_F 0.02209708691207961f
#define LN_EPS_F 1e-5f

DEV float b2f(short h) { return __uint_as_float(((unsigned)(unsigned short)h) << 16); }
DEV short f2b(float f) {
  __hip_bfloat16 h = __float2bfloat16(f);
  return *reinterpret_cast<short*>(&h);
}

// async global->LDS, 16B per lane. LDS dest is wave-uniform base + lane*16.
// Integer-cast pointer formation: AS(1) keeps the 64-bit address (global==flat
// numerically); AS(3) takes low 32 bits (LDS aperture is high-aligned, so the
// truncated value IS the group offset).
DEV void gload_lds16(const void* g, void* l) {
  __builtin_amdgcn_global_load_lds(
      (const __attribute__((address_space(1))) unsigned int*)(unsigned long long)g,
      (__attribute__((address_space(3))) unsigned int*)(unsigned int)(unsigned long long)l,
      16, 0, 0);
}

// ---------------- fp32 -> bf16 casts ----------------
__global__ __launch_bounds__(256) void castA_kernel(const float* s, short* d, int n) {
  const int i = (blockIdx.x * 256 + threadIdx.x) * 8;
  if (i >= n) return;
  float4 a = *(const float4*)(s + i);
  float4 b = *(const float4*)(s + i + 4);
  s16x8 o;
  o[0] = f2b(a.x); o[1] = f2b(a.y); o[2] = f2b(a.z); o[3] = f2b(a.w);
  o[4] = f2b(b.x); o[5] = f2b(b.y); o[6] = f2b(b.z); o[7] = f2b(b.w);
  *(s16x8*)(d + i) = o;
}

struct Cast2 { const float* s[2]; short* d[2]; };

__global__ __launch_bounds__(256) void cast2_kernel(Cast2 j, int n) {
  const int jb = blockIdx.y;
  const int i = (blockIdx.x * 256 + threadIdx.x) * 8;
  if (i >= n) return;
  const float* src = j.s[jb] + i;
  float4 a = *(const float4*)(src);
  float4 b = *(const float4*)(src + 4);
  s16x8 o;
  o[0] = f2b(a.x); o[1] = f2b(a.y); o[2] = f2b(a.z); o[3] = f2b(a.w);
  o[4] = f2b(b.x); o[5] = f2b(b.y); o[6] = f2b(b.z); o[7] = f2b(b.w);
  *(s16x8*)(j.d[jb] + i) = o;
}

// ---------------- fp32 -> bf16 transposing cast: WT[d][e] = W[e][d] ----------
struct Cast4T { const float* s[4]; short* d[4]; };

__global__ __launch_bounds__(256) void castT_kernel(Cast4T j) {
  __shared__ float tl[64][65];  // [d][e], padded
  const int z = blockIdx.z;
  const float* src = j.s[z];
  short* dst = j.d[z];
  const int e0 = blockIdx.x * 64, d0 = blockIdx.y * 64;
  const int t = threadIdx.x;
  // load 64(e) x 64(d) fp32, store transposed into LDS
  for (int i = t; i < 64 * 16; i += 256) {
    const int er = i >> 4, c4 = (i & 15) * 4;
    const float4 v = *(const float4*)(src + (long)(e0 + er) * 2048 + d0 + c4);
    tl[c4 + 0][er] = v.x;
    tl[c4 + 1][er] = v.y;
    tl[c4 + 2][er] = v.z;
    tl[c4 + 3][er] = v.w;
  }
  __syncthreads();
  // write 64(d) x 64(e) bf16
  for (int i = t; i < 64 * 8; i += 256) {
    const int dr = i >> 3, e8 = (i & 7) * 8;
    s16x8 o;
#pragma unroll
    for (int e = 0; e < 8; ++e) o[e] = f2b(tl[dr][e8 + e]);
    *(s16x8*)(dst + (long)(d0 + dr) * 2048 + e0 + e8) = o;
  }
}

// ---------------- prep: constant softmax masks + q-bias fold vectors --------
// block 0:     wm[0..11]  = softmax_j( sum_n nsa_fc_w[j,n] + nsa_fc_b[j] )
//              wm[16..100]= softmax_u( sum_w sa_fc_w[u,w] + sa_fc_b[u] )
// blocks 1-128: r{1,2}[dp] += sum_{e in chunk} bq[e]*wk[e,dp]   (atomics; r pre-zeroed)
//   idx=bx-1: stage=idx>>6, echunk=(idx&63)>>3, dpchunk=idx&7
__global__ __launch_bounds__(256) void prep_kernel(const float* nw, const float* nb,
                                                   const float* sw, const float* sb, float* wm,
                                                   const float* wk1, const float* bq1, float* r1,
                                                   const float* wk2, const float* bq2, float* r2) {
  const int bx = blockIdx.x, t = threadIdx.x;
  if (bx == 0) {
    __shared__ float l1[12], l2[85];
    if (t < 12) { float s = nb[t]; for (int n = 0; n < 12; ++n) s += nw[t * 12 + n]; l1[t] = s; }
    if (t < 85) { float s = sb[t]; for (int w = 0; w < 85; ++w) s += sw[t * 85 + w]; l2[t] = s; }
    __syncthreads();
    if (t == 0) {
      float m = l1[0]; for (int i = 1; i < 12; ++i) m = fmaxf(m, l1[i]);
      float s = 0.f; float e[12];
      for (int i = 0; i < 12; ++i) { e[i] = expf(l1[i] - m); s += e[i]; }
      for (int i = 0; i < 12; ++i) wm[i] = e[i] / s;
    } else if (t == 64) {
      float m = l2[0]; for (int i = 1; i < 85; ++i) m = fmaxf(m, l2[i]);
      float s = 0.f;
      for (int i = 0; i < 85; ++i) s += expf(l2[i] - m);
      for (int i = 0; i < 85; ++i) wm[16 + i] = expf(l2[i] - m) / s;
    }
    return;
  }
  const int idx = bx - 1;
  const int stage = idx >> 6;
  const int ec = (idx & 63) >> 3, dpc = idx & 7;
  const float* wk = stage ? wk2 : wk1;
  const float* bq = stage ? bq2 : bq1;
  float* r = stage ? r2 : r1;
  const int dp = dpc * 256 + t;
  const int e0 = ec * 256;
  float s = 0.f;
  for (int e = e0; e < e0 + 256; ++e) s += bq[e] * wk[(long)e * 2048 + dp];
  atomicAdd(&r[dp], s);
}

// ---------------- bf16 MFMA GEMM: C[.,2048] = A @ W^T (+ col bias) ----------
// m97 structure: 128x128 tile, BK=32, global_load_lds width 16, 2-barrier loop.
// LDS layout [kgroup][row][8bf16]: frag ds_read_b128 ~conflict-free, staging
// linear (wave w stages kgroup w; dest = uniform base + lane*16).
// OM=0: bf16 output. OM=1: fp32 output. Rows >= mlim are not stored.
struct GemmArgs {
  const short* A[3];
  const short* Wt[3];
  const float* bias[3];
  void* C[3];
  int mlim;
};

template <int OM>
__global__ __launch_bounds__(256) void gemm_nt_bf16(GemmArgs g) {
  __shared__ short As[4096];  // 8 KB = 4 kg * 128 rows * 16B
  __shared__ short Bs[4096];
  const int z = blockIdx.z;
  const short* A = g.A[z];
  const short* Wm = g.Wt[z];
  const int tid = threadIdx.x, wave = tid >> 6, lane = tid & 63;
  const int wmo = (wave >> 1) * 64, wno = (wave & 1) * 64;
  const long rowA0 = (long)blockIdx.x * 128;
  const long rowB0 = (long)blockIdx.y * 128;
  const int kg = lane >> 4, rsub = lane & 15;

  f32x4 acc[4][4];
  const f32x4 zz = {0.f, 0.f, 0.f, 0.f};
#pragma unroll
  for (int i = 0; i < 4; ++i)
#pragma unroll
    for (int jj = 0; jj < 4; ++jj) acc[i][jj] = zz;

  for (int kt = 0; kt < 64; ++kt) {
    const int kbase = kt * 32;
    __syncthreads();  // previous tile fully consumed
#pragma unroll
    for (int i = 0; i < 2; ++i) {
      const int row = i * 64 + lane;
      gload_lds16(A + (rowA0 + row) * 2048 + kbase + wave * 8,
                  (char*)As + (wave * 128 + i * 64) * 16);
      gload_lds16(Wm + (rowB0 + row) * 2048 + kbase + wave * 8,
                  (char*)Bs + (wave * 128 + i * 64) * 16);
    }
    __syncthreads();  // compiler drains vmcnt(0) here: tile resident
    s16x8 af[4], bv[4];
#pragma unroll
    for (int f = 0; f < 4; ++f) {
      af[f] = *(const s16x8*)(As + (kg * 128 + wmo + f * 16 + rsub) * 8);
      bv[f] = *(const s16x8*)(Bs + (kg * 128 + wno + f * 16 + rsub) * 8);
    }
#pragma unroll
    for (int i = 0; i < 4; ++i)
#pragma unroll
      for (int jj = 0; jj < 4; ++jj)
        acc[i][jj] = __builtin_amdgcn_mfma_f32_16x16x32_bf16(af[i], bv[jj], acc[i][jj], 0, 0, 0);
  }

  const float* bias = g.bias[z];
  const int crow = (lane >> 4) * 4, ccol = lane & 15;
#pragma unroll
  for (int i = 0; i < 4; ++i) {
    const long row = rowA0 + wmo + i * 16 + crow;
#pragma unroll
    for (int jj = 0; jj < 4; ++jj) {
      const long col = rowB0 + wno + jj * 16 + ccol;
      const float bvl = bias ? bias[col] : 0.f;
#pragma unroll
      for (int r = 0; r < 4; ++r) {
        if (row + r < g.mlim) {
          if (OM == 0)
            ((short*)g.C[z])[(row + r) * 2048 + col] = f2b(acc[i][jj][r] + bvl);
          else
            ((float*)g.C[z])[(row + r) * 2048 + col] = acc[i][jj][r] + bvl;
        }
      }
    }
  }
}

// ---------------- attn1: banded dots  G[b,i,j] = dot(Y1[b,i], A1[b,j]), |i-j|<=11
__global__ __launch_bounds__(256) void attn1_g_kernel(const short* qp, const short* kp, float* G) {
  const int b = blockIdx.y, ig = blockIdx.x;
  const int t = threadIdx.x;
  for (int p = t; p < 16 * 23; p += 256) {
    const int ii = p / 23, dj = p % 23 - 11;
    const int i = ig * 16 + ii, jj = i + dj;
    if (jj < 0 || jj >= 96) continue;
    const short* q = qp + ((long)b * 96 + i) * 2048;
    const short* k = kp + ((long)b * 96 + jj) * 2048;
    float s = 0.f;
    for (int d = 0; d < 2048; d += 8) {
      s16x8 qv = *(const s16x8*)(q + d);
      s16x8 kv = *(const s16x8*)(k + d);
#pragma unroll
      for (int e = 0; e < 8; ++e) s += b2f(qv[e]) * b2f(kv[e]);
    }
    G[((long)b * 96 + i) * 96 + jj] = s;
  }
}

// softmax over the 12x12 window + fold wmask: p1[b,w,m] = sum_n wm[n]*attn[n,m]
__global__ __launch_bounds__(64) void attn1_soft_kernel(const float* G, const float* wm, float* p1) {
  const int w = blockIdx.x, b = blockIdx.y;
  const int lane = threadIdx.x;
  __shared__ float at[12][12];
  __shared__ float coef[12];
  if (lane < 12) {
    float row[12]; float mx = -1e30f;
    for (int m = 0; m < 12; ++m) {
      row[m] = G[((long)b * 96 + w + lane) * 96 + w + m] * SCALE_F;
      mx = fmaxf(mx, row[m]);
    }
    float s = 0.f;
    for (int m = 0; m < 12; ++m) { float e = expf(row[m] - mx); at[lane][m] = e; s += e; }
    coef[lane] = wm[lane] / s;
  }
  __syncthreads();
  if (lane < 12) {
    float a = 0.f;
    for (int n = 0; n < 12; ++n) a += at[n][lane] * coef[n];
    p1[((long)b * 85 + w) * 12 + lane] = a;
  }
}

// ---------------- x = ds_w-downsample (fp32 fc) + nsa_feats, fp32 out --------
__global__ __launch_bounds__(256) void combine_kernel(const float* fc32, const short* vp,
                                                      const float* p1, const float* dsw_g,
                                                      const float* dsb, float* X) {
  const int b = blockIdx.y, d0 = blockIdx.x * 128;
  const int t = threadIdx.x;
  __shared__ float fcs[96][128];   // 48 KB
  __shared__ short vps[96][128];   // 24 KB
  __shared__ float dsw[85][96];    // 31.9 KB
  __shared__ float p1s[85][12];    // 4 KB
  for (int s = t; s < 96 * 32; s += 256) {
    const int row = s >> 5, c4 = (s & 31) * 4;
    *(float4*)&fcs[row][c4] = *(const float4*)(fc32 + ((long)b * 96 + row) * 2048 + d0 + c4);
  }
  for (int s = t; s < 96 * 16; s += 256) {
    const int row = s >> 4, c8 = (s & 15) * 8;
    *(s16x8*)&vps[row][c8] = *(const s16x8*)(vp + ((long)b * 96 + row) * 2048 + d0 + c8);
  }
  for (int s = t; s < 85 * 96; s += 256) (&dsw[0][0])[s] = dsw_g[s];
  for (int s = t; s < 85 * 12; s += 256) (&p1s[0][0])[s] = p1[(long)b * 85 * 12 + s];
  __syncthreads();
  const int dp = (t & 63) * 2, wslot = t >> 6;
  for (int w = wslot; w < 85; w += 4) {
    float a0 = dsb[w], a1 = a0;
    for (int p = 0; p < 96; ++p) {
      const float c = dsw[w][p];
      a0 += c * fcs[p][dp];
      a1 += c * fcs[p][dp + 1];
    }
#pragma unroll
    for (int m = 0; m < 12; ++m) {
      const unsigned vv = *(const unsigned*)&vps[w + m][dp];
      const float c = p1s[w][m];
      a0 += c * __uint_as_float(vv << 16);
      a1 += c * __uint_as_float(vv & 0xffff0000u);
    }
    const long o = ((long)b * 85 + w) * 2048 + d0 + dp;
    X[o] = a0;
    X[o + 1] = a1;
  }
}

// ---------------- LayerNorm over D: fp32 in, bf16 out ----------------
__global__ __launch_bounds__(256) void ln_kernel(const float* X, const float* gam,
                                                 const float* bet, short* XLN) {
  const long row = blockIdx.x;
  const int t = threadIdx.x;
  float v[8];
  *(float4*)&v[0] = *(const float4*)(X + row * 2048 + t * 8);
  *(float4*)&v[4] = *(const float4*)(X + row * 2048 + t * 8 + 4);
  float s = 0.f, q = 0.f;
#pragma unroll
  for (int e = 0; e < 8; ++e) { s += v[e]; q += v[e] * v[e]; }
#pragma unroll
  for (int o = 32; o > 0; o >>= 1) { s += __shfl_down(s, o); q += __shfl_down(q, o); }
  __shared__ float rs[4], rq[4];
  if ((t & 63) == 0) { rs[t >> 6] = s; rq[t >> 6] = q; }
  __syncthreads();
  const float S = rs[0] + rs[1] + rs[2] + rs[3];
  const float Q = rq[0] + rq[1] + rq[2] + rq[3];
  const float mu = S * (1.f / 2048.f);
  const float var = Q * (1.f / 2048.f) - mu * mu;
  const float rstd = rsqrtf(var + LN_EPS_F);
  s16x8 o8;
#pragma unroll
  for (int e = 0; e < 8; ++e) {
    const int c = t * 8 + e;
    o8[e] = f2b((v[e] - mu) * rstd * gam[c] + bet[c]);
  }
  *(s16x8*)(XLN + row * 2048 + t * 8) = o8;
}

// ---------------- attn2: 8 q-rows per block, fold wmask2 -> p2[b,u] ----------
__global__ __launch_bounds__(256) void attn2_kernel(const short* y2, const short* xln,
                                                    const float* wm2, float* p2) {
  const int b = blockIdx.y, w0 = blockIdx.x * 8;
  const int t = threadIdx.x;
  __shared__ short qs[8][2048];
  __shared__ float sc[8][85];
  __shared__ float coef[8];
  for (int s = t; s < 8 * 256; s += 256) {
    const int rr = s >> 8, c8 = (s & 255) * 8;
    const int w = w0 + rr;
    s16x8 val;
    if (w < 85) val = *(const s16x8*)(y2 + ((long)b * 85 + w) * 2048 + c8);
    else {
#pragma unroll
      for (int e = 0; e < 8; ++e) val[e] = 0;
    }
    *(s16x8*)&qs[rr][c8] = val;
  }
  __syncthreads();
  for (int pi = t; pi < 680; pi += 256) {
    const int rr = pi / 85, u = pi % 85;
    const short* kr = xln + ((long)b * 85 + u) * 2048;
    float s = 0.f;
    for (int d = 0; d < 2048; d += 8) {
      s16x8 qv = *(const s16x8*)&qs[rr][d];
      s16x8 kv = *(const s16x8*)(kr + d);
#pragma unroll
      for (int e = 0; e < 8; ++e) s += b2f(qv[e]) * b2f(kv[e]);
    }
    sc[rr][u] = s * SCALE_F;
  }
  __syncthreads();
  if (t < 8) {
    float mx = -1e30f;
    for (int u = 0; u < 85; ++u) mx = fmaxf(mx, sc[t][u]);
    float sum = 0.f;
    for (int u = 0; u < 85; ++u) { const float e = expf(sc[t][u] - mx); sc[t][u] = e; sum += e; }
    coef[t] = (w0 + t < 85) ? wm2[w0 + t] / sum : 0.f;
  }
  __syncthreads();
  if (t < 85) {
    float a = 0.f;
#pragma unroll
    for (int rr = 0; rr < 8; ++rr) a += sc[rr][t] * coef[rr];
    atomicAdd(&p2[b * 85 + t], a);
  }
}

// ---------------- z2[b,d] = sum_u p2[b,u] * xln[b,u,d]  (bf16, rows 64..127 = 0)
__global__ __launch_bounds__(256) void z2_kernel(const short* xln, const float* p2, short* z2) {
  const int b = blockIdx.y, d = blockIdx.x * 256 + threadIdx.x;
  if (b >= 64) { z2[(long)b * 2048 + d] = 0; return; }
  __shared__ float pc[85];
  if (threadIdx.x < 85) pc[threadIdx.x] = p2[b * 85 + threadIdx.x];
  __syncthreads();
  float a = 0.f;
  for (int u = 0; u < 85; ++u) a += pc[u] * b2f(xln[((long)b * 85 + u) * 2048 + d]);
  z2[(long)b * 2048 + d] = f2b(a);
}

extern "C" void kernel_launch(void* const* d_in, const int* in_sizes, int n_in,
                              void* d_out, int out_size, void* d_ws, size_t ws_size,
                              hipStream_t stream) {
  char* ws = (char*)d_ws;
  size_t off = 0;
  auto alloc = [&](size_t bytes) -> char* {
    char* p = ws + off;
    off += (bytes + 255) & ~(size_t)255;
    return p;
  };

  // Buffer plan (~187 MB) with lifetime aliasing:
  //   A1: fc bf16, dead after attn1_g -> XLN (ln out, stage-2 A operand)
  //   Y1: stage-1 folded-QK scores operand, dead after attn1_g -> Y2
  short* A1   = (short*)alloc((size_t)M1_ * D_ * 2);   // 24 MB
  short* WqT1 = (short*)alloc((size_t)D_ * D_ * 2);    // 8.4 MB
  short* WkT1 = (short*)alloc((size_t)D_ * D_ * 2);
  short* WqT2 = (short*)alloc((size_t)D_ * D_ * 2);
  short* WkT2 = (short*)alloc((size_t)D_ * D_ * 2);
  short* Gt1  = (short*)alloc((size_t)D_ * D_ * 2);
  short* Gt2  = (short*)alloc((size_t)D_ * D_ * 2);
  short* Wv1c = (short*)alloc((size_t)D_ * D_ * 2);
  short* Wv2c = (short*)alloc((size_t)D_ * D_ * 2);
  short* Y1   = (short*)alloc((size_t)M1_ * D_ * 2);   // 24 MB
  short* VP   = (short*)alloc((size_t)M1_ * D_ * 2);   // 24 MB
  float* X    = (float*)alloc((size_t)M2_ * D_ * 4);   // 44.6 MB
  float* G    = (float*)alloc((size_t)B_ * 96 * 96 * 4);
  float* P1   = (float*)alloc((size_t)B_ * W_ * N_ * 4);
  short* Z2   = (short*)alloc((size_t)128 * D_ * 2);
  float* P2   = (float*)alloc((size_t)B_ * W_ * 4);   // zeroed (contiguous with WM/R1/R2)
  float* WM   = (float*)alloc(512);
  float* R1   = (float*)alloc(D_ * 4);
  float* R2   = (float*)alloc(D_ * 4);

  short* XLN = A1;  // 5504*2048*2 = 22.5 MB <= A1 (24 MB)
  short* Y2  = Y1;  // 5504 rows  <= Y1 (6144 rows)

  if (off > ws_size) return;  // ws too small: bail (validation will flag it)

  // zero P2 + WM + R1 + R2 in one contiguous memset (re-done every replay)
  const size_t zbytes = (size_t)((char*)R2 - (char*)P2) + D_ * 4;
  hipMemsetAsync(P2, 0, zbytes, stream);

  // --- weight prep (all independent of activations) ---
  castA_kernel<<<dim3(6144), 256, 0, stream>>>((const float*)d_in[0], A1, M1_ * D_);
  Cast4T ct;
  ct.s[0] = (const float*)d_in[1];  ct.d[0] = WqT1;
  ct.s[1] = (const float*)d_in[3];  ct.d[1] = WkT1;
  ct.s[2] = (const float*)d_in[13]; ct.d[2] = WqT2;
  ct.s[3] = (const float*)d_in[15]; ct.d[3] = WkT2;
  castT_kernel<<<dim3(32, 32, 4), 256, 0, stream>>>(ct);
  Cast2 cv;
  cv.s[0] = (const float*)d_in[5];  cv.d[0] = Wv1c;
  cv.s[1] = (const float*)d_in[17]; cv.d[1] = Wv2c;
  cast2_kernel<<<dim3(2048, 2), 256, 0, stream>>>(cv, D_ * D_);
  prep_kernel<<<dim3(129), 256, 0, stream>>>(
      (const float*)d_in[7], (const float*)d_in[8],
      (const float*)d_in[19], (const float*)d_in[20], WM,
      (const float*)d_in[3], (const float*)d_in[2], R1,
      (const float*)d_in[15], (const float*)d_in[14], R2);

  // Gt = (Wk^T) @ (Wq^T)^T, i.e. Gt[d',d] = sum_e Wk[e,d']*Wq[e,d]
  GemmArgs gg;
  gg.A[0] = WkT1; gg.Wt[0] = WqT1; gg.bias[0] = nullptr; gg.C[0] = Gt1;
  gg.A[1] = WkT2; gg.Wt[1] = WqT2; gg.bias[1] = nullptr; gg.C[1] = Gt2;
  gg.mlim = 2048;
  gemm_nt_bf16<0><<<dim3(16, 16, 2), 256, 0, stream>>>(gg);

  // stage-1: VP = A1@Wv1^T + bv1 ; Y1 = A1@Gt1^T + r1
  GemmArgs g1;
  g1.A[0] = A1; g1.Wt[0] = Wv1c; g1.bias[0] = (const float*)d_in[6]; g1.C[0] = VP;
  g1.A[1] = A1; g1.Wt[1] = Gt1;  g1.bias[1] = R1;                    g1.C[1] = Y1;
  g1.mlim = M1_;
  gemm_nt_bf16<0><<<dim3(48, 16, 2), 256, 0, stream>>>(g1);

  attn1_g_kernel<<<dim3(6, 64), 256, 0, stream>>>(Y1, A1, G);
  attn1_soft_kernel<<<dim3(85, 64), 64, 0, stream>>>(G, WM, P1);
  combine_kernel<<<dim3(16, 64), 256, 0, stream>>>((const float*)d_in[0], VP, P1,
                                                   (const float*)d_in[9],
                                                   (const float*)d_in[10], X);
  ln_kernel<<<dim3(5440), 256, 0, stream>>>(X, (const float*)d_in[11], (const float*)d_in[12], XLN);

  // stage-2: Y2 = XLN@Gt2^T + r2  (V2 GEMM eliminated via z2 folding)
  GemmArgs g2;
  g2.A[0] = XLN; g2.Wt[0] = Gt2; g2.bias[0] = R2; g2.C[0] = Y2;
  g2.mlim = M2P_;
  gemm_nt_bf16<0><<<dim3(43, 16, 1), 256, 0, stream>>>(g2);

  attn2_kernel<<<dim3(11, 64), 256, 0, stream>>>(Y2, XLN, WM + 16, P2);
  z2_kernel<<<dim3(8, 128), 256, 0, stream>>>(XLN, P2, Z2);

  // out = Z2 @ Wv2^T + bv2, fp32 epilogue straight into d_out (rows < 64)
  GemmArgs go;
  go.A[0] = Z2; go.Wt[0] = Wv2c; go.bias[0] = (const float*)d_in[18]; go.C[0] = d_out;
  go.mlim = 64;
  gemm_nt_bf16<1><<<dim3(1, 16, 1), 256, 0, stream>>>(go);
}

// Round 6
// 889.869 us; speedup vs baseline: 1.4067x; 1.4067x over previous
//
#include <hip/hip_runtime.h>
#include <hip/hip_bf16.h>

#define DEV __device__ __forceinline__

typedef __attribute__((ext_vector_type(8))) short s16x8;
typedef __attribute__((ext_vector_type(4))) float f32x4;

#define B_ 64
#define P_ 96
#define N_ 12
#define D_ 2048
#define W_ 85
#define M1_ (B_ * P_)   // 6144 rows stage-1
#define M2_ (B_ * W_)   // 5440 rows stage-2
#define M2P_ 5504       // padded to 43*128
#define SCALE_F 0.02209708691207961f
#define LN_EPS_F 1e-5f

DEV float b2f(short h) { return __uint_as_float(((unsigned)(unsigned short)h) << 16); }
DEV short f2b(float f) {
  __hip_bfloat16 h = __float2bfloat16(f);
  return *reinterpret_cast<short*>(&h);
}

// async global->LDS, 16B per lane. LDS dest is wave-uniform base + lane*16.
DEV void gload_lds16(const void* g, void* l) {
  __builtin_amdgcn_global_load_lds(
      (const __attribute__((address_space(1))) unsigned int*)(unsigned long long)g,
      (__attribute__((address_space(3))) unsigned int*)(unsigned int)(unsigned long long)l,
      16, 0, 0);
}

// ---------------- fp32 -> bf16 casts ----------------
__global__ __launch_bounds__(256) void castA_kernel(const float* s, short* d, int n) {
  const int i = (blockIdx.x * 256 + threadIdx.x) * 8;
  if (i >= n) return;
  float4 a = *(const float4*)(s + i);
  float4 b = *(const float4*)(s + i + 4);
  s16x8 o;
  o[0] = f2b(a.x); o[1] = f2b(a.y); o[2] = f2b(a.z); o[3] = f2b(a.w);
  o[4] = f2b(b.x); o[5] = f2b(b.y); o[6] = f2b(b.z); o[7] = f2b(b.w);
  *(s16x8*)(d + i) = o;
}

struct Cast2 { const float* s[2]; short* d[2]; };

__global__ __launch_bounds__(256) void cast2_kernel(Cast2 j, int n) {
  const int jb = blockIdx.y;
  const int i = (blockIdx.x * 256 + threadIdx.x) * 8;
  if (i >= n) return;
  const float* src = j.s[jb] + i;
  float4 a = *(const float4*)(src);
  float4 b = *(const float4*)(src + 4);
  s16x8 o;
  o[0] = f2b(a.x); o[1] = f2b(a.y); o[2] = f2b(a.z); o[3] = f2b(a.w);
  o[4] = f2b(b.x); o[5] = f2b(b.y); o[6] = f2b(b.z); o[7] = f2b(b.w);
  *(s16x8*)(j.d[jb] + i) = o;
}

// ---------------- fp32 -> bf16 transposing cast: WT[d][e] = W[e][d] ----------
struct Cast4T { const float* s[4]; short* d[4]; };

__global__ __launch_bounds__(256) void castT_kernel(Cast4T j) {
  __shared__ float tl[64][65];  // [d][e], padded
  const int z = blockIdx.z;
  const float* src = j.s[z];
  short* dst = j.d[z];
  const int e0 = blockIdx.x * 64, d0 = blockIdx.y * 64;
  const int t = threadIdx.x;
  for (int i = t; i < 64 * 16; i += 256) {
    const int er = i >> 4, c4 = (i & 15) * 4;
    const float4 v = *(const float4*)(src + (long)(e0 + er) * 2048 + d0 + c4);
    tl[c4 + 0][er] = v.x;
    tl[c4 + 1][er] = v.y;
    tl[c4 + 2][er] = v.z;
    tl[c4 + 3][er] = v.w;
  }
  __syncthreads();
  for (int i = t; i < 64 * 8; i += 256) {
    const int dr = i >> 3, e8 = (i & 7) * 8;
    s16x8 o;
#pragma unroll
    for (int e = 0; e < 8; ++e) o[e] = f2b(tl[dr][e8 + e]);
    *(s16x8*)(dst + (long)(d0 + dr) * 2048 + e0 + e8) = o;
  }
}

// ---------------- prep: constant softmax masks + q-bias fold vectors --------
__global__ __launch_bounds__(256) void prep_kernel(const float* nw, const float* nb,
                                                   const float* sw, const float* sb, float* wm,
                                                   const float* wk1, const float* bq1, float* r1,
                                                   const float* wk2, const float* bq2, float* r2) {
  const int bx = blockIdx.x, t = threadIdx.x;
  if (bx == 0) {
    __shared__ float l1[12], l2[85];
    if (t < 12) { float s = nb[t]; for (int n = 0; n < 12; ++n) s += nw[t * 12 + n]; l1[t] = s; }
    if (t < 85) { float s = sb[t]; for (int w = 0; w < 85; ++w) s += sw[t * 85 + w]; l2[t] = s; }
    __syncthreads();
    if (t == 0) {
      float m = l1[0]; for (int i = 1; i < 12; ++i) m = fmaxf(m, l1[i]);
      float s = 0.f; float e[12];
      for (int i = 0; i < 12; ++i) { e[i] = expf(l1[i] - m); s += e[i]; }
      for (int i = 0; i < 12; ++i) wm[i] = e[i] / s;
    } else if (t == 64) {
      float m = l2[0]; for (int i = 1; i < 85; ++i) m = fmaxf(m, l2[i]);
      float s = 0.f;
      for (int i = 0; i < 85; ++i) s += expf(l2[i] - m);
      for (int i = 0; i < 85; ++i) wm[16 + i] = expf(l2[i] - m) / s;
    }
    return;
  }
  const int idx = bx - 1;
  const int stage = idx >> 6;
  const int ec = (idx & 63) >> 3, dpc = idx & 7;
  const float* wk = stage ? wk2 : wk1;
  const float* bq = stage ? bq2 : bq1;
  float* r = stage ? r2 : r1;
  const int dp = dpc * 256 + t;
  const int e0 = ec * 256;
  float s = 0.f;
  for (int e = e0; e < e0 + 256; ++e) s += bq[e] * wk[(long)e * 2048 + dp];
  atomicAdd(&r[dp], s);
}

// ---------------- bf16 MFMA GEMM: C[.,2048] = A @ W^T (+ col bias) ----------
struct GemmArgs {
  const short* A[3];
  const short* Wt[3];
  const float* bias[3];
  void* C[3];
  int mlim;
};

template <int OM>
__global__ __launch_bounds__(256) void gemm_nt_bf16(GemmArgs g) {
  __shared__ short As[4096];  // 8 KB = 4 kg * 128 rows * 16B
  __shared__ short Bs[4096];
  const int z = blockIdx.z;
  const short* A = g.A[z];
  const short* Wm = g.Wt[z];
  const int tid = threadIdx.x, wave = tid >> 6, lane = tid & 63;
  const int wmo = (wave >> 1) * 64, wno = (wave & 1) * 64;
  const long rowA0 = (long)blockIdx.x * 128;
  const long rowB0 = (long)blockIdx.y * 128;
  const int kg = lane >> 4, rsub = lane & 15;

  f32x4 acc[4][4];
  const f32x4 zz = {0.f, 0.f, 0.f, 0.f};
#pragma unroll
  for (int i = 0; i < 4; ++i)
#pragma unroll
    for (int jj = 0; jj < 4; ++jj) acc[i][jj] = zz;

  for (int kt = 0; kt < 64; ++kt) {
    const int kbase = kt * 32;
    __syncthreads();
#pragma unroll
    for (int i = 0; i < 2; ++i) {
      const int row = i * 64 + lane;
      gload_lds16(A + (rowA0 + row) * 2048 + kbase + wave * 8,
                  (char*)As + (wave * 128 + i * 64) * 16);
      gload_lds16(Wm + (rowB0 + row) * 2048 + kbase + wave * 8,
                  (char*)Bs + (wave * 128 + i * 64) * 16);
    }
    __syncthreads();
    s16x8 af[4], bv[4];
#pragma unroll
    for (int f = 0; f < 4; ++f) {
      af[f] = *(const s16x8*)(As + (kg * 128 + wmo + f * 16 + rsub) * 8);
      bv[f] = *(const s16x8*)(Bs + (kg * 128 + wno + f * 16 + rsub) * 8);
    }
#pragma unroll
    for (int i = 0; i < 4; ++i)
#pragma unroll
      for (int jj = 0; jj < 4; ++jj)
        acc[i][jj] = __builtin_amdgcn_mfma_f32_16x16x32_bf16(af[i], bv[jj], acc[i][jj], 0, 0, 0);
  }

  const float* bias = g.bias[z];
#pragma unroll
  for (int i = 0; i < 4; ++i) {
    const long row = rowA0 + wmo + i * 16 + (lane >> 4) * 4;
#pragma unroll
    for (int jj = 0; jj < 4; ++jj) {
      const long col = rowB0 + wno + jj * 16 + (lane & 15);
      const float bvl = bias ? bias[col] : 0.f;
#pragma unroll
      for (int r = 0; r < 4; ++r) {
        if (row + r < g.mlim) {
          if (OM == 0)
            ((short*)g.C[z])[(row + r) * 2048 + col] = f2b(acc[i][jj][r] + bvl);
          else
            ((float*)g.C[z])[(row + r) * 2048 + col] = acc[i][jj][r] + bvl;
        }
      }
    }
  }
}

// ---------------- batched MFMA attention scores + fused wmask softmax -------
// One block per batch. S[i][j] = dot(Aq_row_i, Bk_row_j) over D=2048, via
// 16x16x32 MFMA, BK=64, global_load_lds staging. Then softmax in-block:
// STAGE1: p1[b,w,m] = sum_n wm[n]*softmax_m(S[w+n][w..w+11]*SCALE)[m]
// STAGE2: p2[b,u]   = sum_i wm2[i]*softmax_u(S[i][0..84]*SCALE)[u]
template <int STAGE>
__global__ __launch_bounds__(256) void attn_mfma_kernel(const short* Aq, const short* Bk,
                                                        const float* wm, float* outp) {
  __shared__ short As[8][96][8];  // 12 KB: [kg][row][8bf16], kg = 8-col chunk
  __shared__ short Bs[8][96][8];  // 12 KB
  __shared__ float S[96][97];     // 37.2 KB scores (+pad)
  __shared__ float C1[85][12];    // coef (stage1) / flat coef (stage2)
  __shared__ float M1[85][12];    // window max (stage1)
  const int b = blockIdx.x;
  const int tid = threadIdx.x, wave = tid >> 6, lane = tid & 63;
  const int RPB = (STAGE == 1) ? 96 : 85;  // rows per batch in global
  const long base = (long)b * RPB * 2048;
  const int wr0 = (wave >> 1) * 48, wc0 = (wave & 1) * 48;
  const int fr = lane & 15, fk = lane >> 4;

  f32x4 acc[3][3];
  const f32x4 zz = {0.f, 0.f, 0.f, 0.f};
#pragma unroll
  for (int i = 0; i < 3; ++i)
#pragma unroll
    for (int j = 0; j < 3; ++j) acc[i][j] = zz;

  for (int kt = 0; kt < 32; ++kt) {
    const int kb = kt * 64;
    __syncthreads();
#pragma unroll
    for (int it = 0; it < 3; ++it) {
      const int u = it * 256 + tid;  // 0..767 ; dest = uniform base + lane*16
      const int row = u % 96, kg = u / 96;
      gload_lds16(Aq + base + (long)row * 2048 + kb + kg * 8, (char*)As + u * 16);
      gload_lds16(Bk + base + (long)row * 2048 + kb + kg * 8, (char*)Bs + u * 16);
    }
    __syncthreads();
#pragma unroll
    for (int ks = 0; ks < 2; ++ks) {
      const int kgx = ks * 4 + fk;
      s16x8 af[3], bv[3];
#pragma unroll
      for (int i = 0; i < 3; ++i) {
        af[i] = *(const s16x8*)&As[kgx][wr0 + i * 16 + fr][0];
        bv[i] = *(const s16x8*)&Bs[kgx][wc0 + i * 16 + fr][0];
      }
#pragma unroll
      for (int i = 0; i < 3; ++i)
#pragma unroll
        for (int j = 0; j < 3; ++j)
          acc[i][j] = __builtin_amdgcn_mfma_f32_16x16x32_bf16(af[i], bv[j], acc[i][j], 0, 0, 0);
    }
  }
  // scores -> LDS  (C/D layout: col=lane&15, row=(lane>>4)*4+reg)
#pragma unroll
  for (int i = 0; i < 3; ++i)
#pragma unroll
    for (int j = 0; j < 3; ++j)
#pragma unroll
      for (int r = 0; r < 4; ++r)
        S[wr0 + i * 16 + fk * 4 + r][wc0 + j * 16 + fr] = acc[i][j][r];
  __syncthreads();

  if (STAGE == 2) {
    if (tid < 85) {
      float mx = -1e30f;
      for (int u = 0; u < 85; ++u) mx = fmaxf(mx, S[tid][u]);
      float sum = 0.f;
      for (int u = 0; u < 85; ++u) {
        const float e = expf((S[tid][u] - mx) * SCALE_F);
        S[tid][u] = e;
        sum += e;
      }
      (&C1[0][0])[tid] = wm[tid] / sum;
    }
    __syncthreads();
    if (tid < 85) {
      float a = 0.f;
      for (int i = 0; i < 85; ++i) a += (&C1[0][0])[i] * S[i][tid];
      outp[b * 85 + tid] = a;
    }
  } else {
    for (int p = tid; p < 85 * 12; p += 256) {
      const int w = p / 12, n = p % 12;
      const int row = w + n;
      float mx = -1e30f;
      for (int m = 0; m < 12; ++m) mx = fmaxf(mx, S[row][w + m]);
      float sum = 0.f;
      for (int m = 0; m < 12; ++m) sum += expf((S[row][w + m] - mx) * SCALE_F);
      M1[w][n] = mx;
      C1[w][n] = wm[n] / sum;
    }
    __syncthreads();
    for (int p = tid; p < 85 * 12; p += 256) {
      const int w = p / 12, m = p % 12;
      float a = 0.f;
#pragma unroll
      for (int n = 0; n < 12; ++n)
        a += C1[w][n] * expf((S[w + n][w + m] - M1[w][n]) * SCALE_F);
      outp[(b * 85 + w) * 12 + m] = a;
    }
  }
}

// ---------------- x = ds_w-downsample (fp32 fc) + nsa_feats, fp32 out --------
__global__ __launch_bounds__(256) void combine_kernel(const float* fc32, const short* vp,
                                                      const float* p1, const float* dsw_g,
                                                      const float* dsb, float* X) {
  const int b = blockIdx.y, d0 = blockIdx.x * 128;
  const int t = threadIdx.x;
  __shared__ float fcs[96][128];   // 48 KB
  __shared__ short vps[96][128];   // 24 KB
  __shared__ float dsw[85][96];    // 31.9 KB
  __shared__ float p1s[85][12];    // 4 KB
  for (int s = t; s < 96 * 32; s += 256) {
    const int row = s >> 5, c4 = (s & 31) * 4;
    *(float4*)&fcs[row][c4] = *(const float4*)(fc32 + ((long)b * 96 + row) * 2048 + d0 + c4);
  }
  for (int s = t; s < 96 * 16; s += 256) {
    const int row = s >> 4, c8 = (s & 15) * 8;
    *(s16x8*)&vps[row][c8] = *(const s16x8*)(vp + ((long)b * 96 + row) * 2048 + d0 + c8);
  }
  for (int s = t; s < 85 * 96; s += 256) (&dsw[0][0])[s] = dsw_g[s];
  for (int s = t; s < 85 * 12; s += 256) (&p1s[0][0])[s] = p1[(long)b * 85 * 12 + s];
  __syncthreads();
  const int dp = (t & 63) * 2, wslot = t >> 6;
  for (int w = wslot; w < 85; w += 4) {
    float a0 = dsb[w], a1 = a0;
    for (int p = 0; p < 96; ++p) {
      const float c = dsw[w][p];
      a0 += c * fcs[p][dp];
      a1 += c * fcs[p][dp + 1];
    }
#pragma unroll
    for (int m = 0; m < 12; ++m) {
      const unsigned vv = *(const unsigned*)&vps[w + m][dp];
      const float c = p1s[w][m];
      a0 += c * __uint_as_float(vv << 16);
      a1 += c * __uint_as_float(vv & 0xffff0000u);
    }
    const long o = ((long)b * 85 + w) * 2048 + d0 + dp;
    X[o] = a0;
    X[o + 1] = a1;
  }
}

// ---------------- LayerNorm over D: fp32 in, bf16 out ----------------
__global__ __launch_bounds__(256) void ln_kernel(const float* X, const float* gam,
                                                 const float* bet, short* XLN) {
  const long row = blockIdx.x;
  const int t = threadIdx.x;
  float v[8];
  *(float4*)&v[0] = *(const float4*)(X + row * 2048 + t * 8);
  *(float4*)&v[4] = *(const float4*)(X + row * 2048 + t * 8 + 4);
  float s = 0.f, q = 0.f;
#pragma unroll
  for (int e = 0; e < 8; ++e) { s += v[e]; q += v[e] * v[e]; }
#pragma unroll
  for (int o = 32; o > 0; o >>= 1) { s += __shfl_down(s, o); q += __shfl_down(q, o); }
  __shared__ float rs[4], rq[4];
  if ((t & 63) == 0) { rs[t >> 6] = s; rq[t >> 6] = q; }
  __syncthreads();
  const float S = rs[0] + rs[1] + rs[2] + rs[3];
  const float Q = rq[0] + rq[1] + rq[2] + rq[3];
  const float mu = S * (1.f / 2048.f);
  const float var = Q * (1.f / 2048.f) - mu * mu;
  const float rstd = rsqrtf(var + LN_EPS_F);
  s16x8 o8;
#pragma unroll
  for (int e = 0; e < 8; ++e) {
    const int c = t * 8 + e;
    o8[e] = f2b((v[e] - mu) * rstd * gam[c] + bet[c]);
  }
  *(s16x8*)(XLN + row * 2048 + t * 8) = o8;
}

// ---------------- z2[b,d] = sum_u p2[b,u] * xln[b,u,d]  (bf16, rows 64..127 = 0)
__global__ __launch_bounds__(256) void z2_kernel(const short* xln, const float* p2, short* z2) {
  const int b = blockIdx.y, d = blockIdx.x * 256 + threadIdx.x;
  if (b >= 64) { z2[(long)b * 2048 + d] = 0; return; }
  __shared__ float pc[85];
  if (threadIdx.x < 85) pc[threadIdx.x] = p2[b * 85 + threadIdx.x];
  __syncthreads();
  float a = 0.f;
  for (int u = 0; u < 85; ++u) a += pc[u] * b2f(xln[((long)b * 85 + u) * 2048 + d]);
  z2[(long)b * 2048 + d] = f2b(a);
}

extern "C" void kernel_launch(void* const* d_in, const int* in_sizes, int n_in,
                              void* d_out, int out_size, void* d_ws, size_t ws_size,
                              hipStream_t stream) {
  char* ws = (char*)d_ws;
  size_t off = 0;
  auto alloc = [&](size_t bytes) -> char* {
    char* p = ws + off;
    off += (bytes + 255) & ~(size_t)255;
    return p;
  };

  short* A1   = (short*)alloc((size_t)M1_ * D_ * 2);   // 24 MB
  short* WqT1 = (short*)alloc((size_t)D_ * D_ * 2);
  short* WkT1 = (short*)alloc((size_t)D_ * D_ * 2);
  short* WqT2 = (short*)alloc((size_t)D_ * D_ * 2);
  short* WkT2 = (short*)alloc((size_t)D_ * D_ * 2);
  short* Gt1  = (short*)alloc((size_t)D_ * D_ * 2);
  short* Gt2  = (short*)alloc((size_t)D_ * D_ * 2);
  short* Wv1c = (short*)alloc((size_t)D_ * D_ * 2);
  short* Wv2c = (short*)alloc((size_t)D_ * D_ * 2);
  short* Y1   = (short*)alloc((size_t)M1_ * D_ * 2);   // 24 MB
  short* VP   = (short*)alloc((size_t)M1_ * D_ * 2);   // 24 MB
  float* X    = (float*)alloc((size_t)M2_ * D_ * 4);   // 44.6 MB
  float* P1   = (float*)alloc((size_t)B_ * W_ * N_ * 4);
  short* Z2   = (short*)alloc((size_t)128 * D_ * 2);
  float* P2   = (float*)alloc((size_t)B_ * W_ * 4);
  float* WM   = (float*)alloc(512);
  float* R1   = (float*)alloc(D_ * 4);
  float* R2   = (float*)alloc(D_ * 4);

  short* XLN = A1;  // 5504*2048*2 = 22.5 MB <= A1 (24 MB)
  short* Y2  = Y1;  // 5504 rows <= Y1 (6144 rows)

  if (off > ws_size) return;

  // zero P2..R2 (contiguous; re-done every replay; R1/R2 are atomic targets)
  const size_t zbytes = (size_t)((char*)R2 - (char*)P2) + D_ * 4;
  hipMemsetAsync(P2, 0, zbytes, stream);

  // --- weight prep ---
  castA_kernel<<<dim3(6144), 256, 0, stream>>>((const float*)d_in[0], A1, M1_ * D_);
  Cast4T ct;
  ct.s[0] = (const float*)d_in[1];  ct.d[0] = WqT1;
  ct.s[1] = (const float*)d_in[3];  ct.d[1] = WkT1;
  ct.s[2] = (const float*)d_in[13]; ct.d[2] = WqT2;
  ct.s[3] = (const float*)d_in[15]; ct.d[3] = WkT2;
  castT_kernel<<<dim3(32, 32, 4), 256, 0, stream>>>(ct);
  Cast2 cv;
  cv.s[0] = (const float*)d_in[5];  cv.d[0] = Wv1c;
  cv.s[1] = (const float*)d_in[17]; cv.d[1] = Wv2c;
  cast2_kernel<<<dim3(2048, 2), 256, 0, stream>>>(cv, D_ * D_);
  prep_kernel<<<dim3(129), 256, 0, stream>>>(
      (const float*)d_in[7], (const float*)d_in[8],
      (const float*)d_in[19], (const float*)d_in[20], WM,
      (const float*)d_in[3], (const float*)d_in[2], R1,
      (const float*)d_in[15], (const float*)d_in[14], R2);

  // Gt = (Wk^T) @ (Wq^T)^T
  GemmArgs gg;
  gg.A[0] = WkT1; gg.Wt[0] = WqT1; gg.bias[0] = nullptr; gg.C[0] = Gt1;
  gg.A[1] = WkT2; gg.Wt[1] = WqT2; gg.bias[1] = nullptr; gg.C[1] = Gt2;
  gg.mlim = 2048;
  gemm_nt_bf16<0><<<dim3(16, 16, 2), 256, 0, stream>>>(gg);

  // stage-1: VP = A1@Wv1^T + bv1 ; Y1 = A1@Gt1^T + r1
  GemmArgs g1;
  g1.A[0] = A1; g1.Wt[0] = Wv1c; g1.bias[0] = (const float*)d_in[6]; g1.C[0] = VP;
  g1.A[1] = A1; g1.Wt[1] = Gt1;  g1.bias[1] = R1;                    g1.C[1] = Y1;
  g1.mlim = M1_;
  gemm_nt_bf16<0><<<dim3(48, 16, 2), 256, 0, stream>>>(g1);

  // fused MFMA scores + softmax (replaces attn1_g + attn1_soft)
  attn_mfma_kernel<1><<<dim3(64), 256, 0, stream>>>(Y1, A1, WM, P1);

  combine_kernel<<<dim3(16, 64), 256, 0, stream>>>((const float*)d_in[0], VP, P1,
                                                   (const float*)d_in[9],
                                                   (const float*)d_in[10], X);
  ln_kernel<<<dim3(5440), 256, 0, stream>>>(X, (const float*)d_in[11], (const float*)d_in[12], XLN);

  // stage-2: Y2 = XLN@Gt2^T + r2
  GemmArgs g2;
  g2.A[0] = XLN; g2.Wt[0] = Gt2; g2.bias[0] = R2; g2.C[0] = Y2;
  g2.mlim = M2P_;
  gemm_nt_bf16<0><<<dim3(43, 16, 1), 256, 0, stream>>>(g2);

  // fused MFMA scores + softmax (replaces attn2), writes p2 directly
  attn_mfma_kernel<2><<<dim3(64), 256, 0, stream>>>(Y2, XLN, WM + 16, P2);

  z2_kernel<<<dim3(8, 128), 256, 0, stream>>>(XLN, P2, Z2);

  // out = Z2 @ Wv2^T + bv2, fp32 epilogue straight into d_out (rows < 64)
  GemmArgs go;
  go.A[0] = Z2; go.Wt[0] = Wv2c; go.bias[0] = (const float*)d_in[18]; go.C[0] = d_out;
  go.mlim = 64;
  gemm_nt_bf16<1><<<dim3(1, 16, 1), 256, 0, stream>>>(go);
}

// Round 8
// 841.655 us; speedup vs baseline: 1.4873x; 1.0573x over previous
//
#include <hip/hip_runtime.h>
#include <hip/hip_bf16.h>

#define DEV __device__ __forceinline__

typedef __attribute__((ext_vector_type(8))) short s16x8;
typedef __attribute__((ext_vector_type(4))) float f32x4;

#define B_ 64
#define P_ 96
#define N_ 12
#define D_ 2048
#define W_ 85
#define M1_ (B_ * P_)   // 6144 rows stage-1
#define M2_ (B_ * W_)   // 5440 rows stage-2
#define M2P_ 5504       // padded to 43*128
#define SCALE_F 0.02209708691207961f
#define LN_EPS_F 1e-5f

DEV float b2f(short h) { return __uint_as_float(((unsigned)(unsigned short)h) << 16); }
DEV short f2b(float f) {
  __hip_bfloat16 h = __float2bfloat16(f);
  return *reinterpret_cast<short*>(&h);
}

// async global->LDS, 16B per lane. LDS dest is wave-uniform base + lane*16.
DEV void gload_lds16(const void* g, void* l) {
  __builtin_amdgcn_global_load_lds(
      (const __attribute__((address_space(1))) unsigned int*)(unsigned long long)g,
      (__attribute__((address_space(3))) unsigned int*)(unsigned int)(unsigned long long)l,
      16, 0, 0);
}

// ---------------- fp32 -> bf16 casts ----------------
__global__ __launch_bounds__(256) void castA_kernel(const float* s, short* d, int n) {
  const int i = (blockIdx.x * 256 + threadIdx.x) * 8;
  if (i >= n) return;
  float4 a = *(const float4*)(s + i);
  float4 b = *(const float4*)(s + i + 4);
  s16x8 o;
  o[0] = f2b(a.x); o[1] = f2b(a.y); o[2] = f2b(a.z); o[3] = f2b(a.w);
  o[4] = f2b(b.x); o[5] = f2b(b.y); o[6] = f2b(b.z); o[7] = f2b(b.w);
  *(s16x8*)(d + i) = o;
}

struct Cast2 { const float* s[2]; short* d[2]; };

__global__ __launch_bounds__(256) void cast2_kernel(Cast2 j, int n) {
  const int jb = blockIdx.y;
  const int i = (blockIdx.x * 256 + threadIdx.x) * 8;
  if (i >= n) return;
  const float* src = j.s[jb] + i;
  float4 a = *(const float4*)(src);
  float4 b = *(const float4*)(src + 4);
  s16x8 o;
  o[0] = f2b(a.x); o[1] = f2b(a.y); o[2] = f2b(a.z); o[3] = f2b(a.w);
  o[4] = f2b(b.x); o[5] = f2b(b.y); o[6] = f2b(b.z); o[7] = f2b(b.w);
  *(s16x8*)(j.d[jb] + i) = o;
}

// ---------------- fp32 -> bf16 transposing cast: WT[d][e] = W[e][d] ----------
struct Cast4T { const float* s[4]; short* d[4]; };

__global__ __launch_bounds__(256) void castT_kernel(Cast4T j) {
  __shared__ float tl[64][65];  // [d][e], padded
  const int z = blockIdx.z;
  const float* src = j.s[z];
  short* dst = j.d[z];
  const int e0 = blockIdx.x * 64, d0 = blockIdx.y * 64;
  const int t = threadIdx.x;
  for (int i = t; i < 64 * 16; i += 256) {
    const int er = i >> 4, c4 = (i & 15) * 4;
    const float4 v = *(const float4*)(src + (long)(e0 + er) * 2048 + d0 + c4);
    tl[c4 + 0][er] = v.x;
    tl[c4 + 1][er] = v.y;
    tl[c4 + 2][er] = v.z;
    tl[c4 + 3][er] = v.w;
  }
  __syncthreads();
  for (int i = t; i < 64 * 8; i += 256) {
    const int dr = i >> 3, e8 = (i & 7) * 8;
    s16x8 o;
#pragma unroll
    for (int e = 0; e < 8; ++e) o[e] = f2b(tl[dr][e8 + e]);
    *(s16x8*)(dst + (long)(d0 + dr) * 2048 + e0 + e8) = o;
  }
}

// ---------------- prep: constant softmax masks + q-bias fold vectors --------
__global__ __launch_bounds__(256) void prep_kernel(const float* nw, const float* nb,
                                                   const float* sw, const float* sb, float* wm,
                                                   const float* wk1, const float* bq1, float* r1,
                                                   const float* wk2, const float* bq2, float* r2) {
  const int bx = blockIdx.x, t = threadIdx.x;
  if (bx == 0) {
    __shared__ float l1[12], l2[85];
    if (t < 12) { float s = nb[t]; for (int n = 0; n < 12; ++n) s += nw[t * 12 + n]; l1[t] = s; }
    if (t < 85) { float s = sb[t]; for (int w = 0; w < 85; ++w) s += sw[t * 85 + w]; l2[t] = s; }
    __syncthreads();
    if (t == 0) {
      float m = l1[0]; for (int i = 1; i < 12; ++i) m = fmaxf(m, l1[i]);
      float s = 0.f; float e[12];
      for (int i = 0; i < 12; ++i) { e[i] = expf(l1[i] - m); s += e[i]; }
      for (int i = 0; i < 12; ++i) wm[i] = e[i] / s;
    } else if (t == 64) {
      float m = l2[0]; for (int i = 1; i < 85; ++i) m = fmaxf(m, l2[i]);
      float s = 0.f;
      for (int i = 0; i < 85; ++i) s += expf(l2[i] - m);
      for (int i = 0; i < 85; ++i) wm[16 + i] = expf(l2[i] - m) / s;
    }
    return;
  }
  const int idx = bx - 1;
  const int stage = idx >> 6;
  const int ec = (idx & 63) >> 3, dpc = idx & 7;
  const float* wk = stage ? wk2 : wk1;
  const float* bq = stage ? bq2 : bq1;
  float* r = stage ? r2 : r1;
  const int dp = dpc * 256 + t;
  const int e0 = ec * 256;
  float s = 0.f;
  for (int e = e0; e < e0 + 256; ++e) s += bq[e] * wk[(long)e * 2048 + dp];
  atomicAdd(&r[dp], s);
}

// ---------------- bf16 MFMA GEMM: C[.,2048] = A @ W^T (+ col bias) ----------
// T3 minimum 2-phase: LDS double-buffer, prefetch next K-tile before current
// tile's ds_read+MFMA, ONE barrier per K-step (compiler drains vmcnt before it).
struct GemmArgs {
  const short* A[3];
  const short* Wt[3];
  const float* bias[3];
  void* C[3];
  int mlim;
};

template <int OM>
__global__ __launch_bounds__(256) void gemm_nt_bf16(GemmArgs g) {
  __shared__ short As[2][4096];  // 2 x 8 KB  [buf][kg][row][8bf16]
  __shared__ short Bs[2][4096];
  const int z = blockIdx.z;
  const short* A = g.A[z];
  const short* Wm = g.Wt[z];
  const int tid = threadIdx.x, wave = tid >> 6, lane = tid & 63;
  const int wmo = (wave >> 1) * 64, wno = (wave & 1) * 64;
  const long rowA0 = (long)blockIdx.x * 128;
  const long rowB0 = (long)blockIdx.y * 128;
  const int kg = lane >> 4, rsub = lane & 15;

  f32x4 acc[4][4];
  const f32x4 zz = {0.f, 0.f, 0.f, 0.f};
#pragma unroll
  for (int i = 0; i < 4; ++i)
#pragma unroll
    for (int jj = 0; jj < 4; ++jj) acc[i][jj] = zz;

  auto stage = [&](int bb, int kbase) {
#pragma unroll
    for (int i = 0; i < 2; ++i) {
      const int row = i * 64 + lane;
      gload_lds16(A + (rowA0 + row) * 2048 + kbase + wave * 8,
                  (char*)As[bb] + (wave * 128 + i * 64) * 16);
      gload_lds16(Wm + (rowB0 + row) * 2048 + kbase + wave * 8,
                  (char*)Bs[bb] + (wave * 128 + i * 64) * 16);
    }
  };

  stage(0, 0);
  __syncthreads();  // tile 0 resident
  for (int kt = 0; kt < 64; ++kt) {
    const int cur = kt & 1;
    if (kt < 63) stage(cur ^ 1, (kt + 1) * 32);  // prefetch flies over MFMAs
    s16x8 af[4], bv[4];
#pragma unroll
    for (int f = 0; f < 4; ++f) {
      af[f] = *(const s16x8*)(As[cur] + (kg * 128 + wmo + f * 16 + rsub) * 8);
      bv[f] = *(const s16x8*)(Bs[cur] + (kg * 128 + wno + f * 16 + rsub) * 8);
    }
#pragma unroll
    for (int i = 0; i < 4; ++i)
#pragma unroll
      for (int jj = 0; jj < 4; ++jj)
        acc[i][jj] = __builtin_amdgcn_mfma_f32_16x16x32_bf16(af[i], bv[jj], acc[i][jj], 0, 0, 0);
    __syncthreads();  // drains this wave's prefetch; all waves ready for swap
  }

  const float* bias = g.bias[z];
#pragma unroll
  for (int i = 0; i < 4; ++i) {
    const long row = rowA0 + wmo + i * 16 + (lane >> 4) * 4;
#pragma unroll
    for (int jj = 0; jj < 4; ++jj) {
      const long col = rowB0 + wno + jj * 16 + (lane & 15);
      const float bvl = bias ? bias[col] : 0.f;
#pragma unroll
      for (int r = 0; r < 4; ++r) {
        if (row + r < g.mlim) {
          if (OM == 0)
            ((short*)g.C[z])[(row + r) * 2048 + col] = f2b(acc[i][jj][r] + bvl);
          else
            ((float*)g.C[z])[(row + r) * 2048 + col] = acc[i][jj][r] + bvl;
        }
      }
    }
  }
}

// ---------------- out = Z2 @ Wv2^T + bv2, K-split, atomic fp32 epilogue -----
// Tile: 64 rows x 128 cols, BK=32, 4 K-slices of 512. d_out pre-zeroed.
__global__ __launch_bounds__(256) void out_gemm_kernel(const short* A, const short* Wm,
                                                       const float* bias, float* C) {
  __shared__ short As[2][4][64][8];   // 2 x 4 KB
  __shared__ short Bs[2][4][128][8];  // 2 x 8 KB
  const int kz = blockIdx.x;  // K-slice
  const long rowB0 = (long)blockIdx.y * 128;
  const int tid = threadIdx.x, wave = tid >> 6, lane = tid & 63;
  const int wno = wave * 32;
  const int kgx = lane >> 4, rsub = lane & 15;

  f32x4 acc[4][2];
  const f32x4 zz = {0.f, 0.f, 0.f, 0.f};
#pragma unroll
  for (int f = 0; f < 4; ++f) { acc[f][0] = zz; acc[f][1] = zz; }

  auto stage = [&](int bb, int kbase) {
    // A: 64 rows x 32 cols in one load/thread (row=lane, kg=wave)
    gload_lds16(A + (long)lane * 2048 + kbase + wave * 8, (char*)As[bb] + tid * 16);
#pragma unroll
    for (int i = 0; i < 2; ++i) {
      const int row = i * 64 + lane;
      gload_lds16(Wm + (rowB0 + row) * 2048 + kbase + wave * 8,
                  (char*)Bs[bb] + (wave * 128 + i * 64) * 16);
    }
  };

  const int kb0 = kz * 512;
  stage(0, kb0);
  __syncthreads();
  for (int kt = 0; kt < 16; ++kt) {
    const int cur = kt & 1;
    if (kt < 15) stage(cur ^ 1, kb0 + (kt + 1) * 32);
    s16x8 af[4], bv[2];
#pragma unroll
    for (int f = 0; f < 4; ++f) af[f] = *(const s16x8*)&As[cur][kgx][f * 16 + rsub][0];
#pragma unroll
    for (int j = 0; j < 2; ++j) bv[j] = *(const s16x8*)&Bs[cur][kgx][wno + j * 16 + rsub][0];
#pragma unroll
    for (int f = 0; f < 4; ++f)
#pragma unroll
      for (int j = 0; j < 2; ++j)
        acc[f][j] = __builtin_amdgcn_mfma_f32_16x16x32_bf16(af[f], bv[j], acc[f][j], 0, 0, 0);
    __syncthreads();
  }

#pragma unroll
  for (int f = 0; f < 4; ++f) {
    const int row = f * 16 + (lane >> 4) * 4;
#pragma unroll
    for (int j = 0; j < 2; ++j) {
      const long col = rowB0 + wno + j * 16 + (lane & 15);
      const float bvl = (kz == 0) ? bias[col] : 0.f;
#pragma unroll
      for (int r = 0; r < 4; ++r)
        atomicAdd(&C[(long)(row + r) * 2048 + col], acc[f][j][r] + bvl);
    }
  }
}

// ---------------- batched MFMA attention scores + fused wmask softmax -------
// One block per batch; dbuf prefetch over the 32 K-steps.
template <int STAGE>
__global__ __launch_bounds__(256) void attn_mfma_kernel(const short* Aq, const short* Bk,
                                                        const float* wm, float* outp) {
  __shared__ short As[2][8][96][8];  // 2 x 12 KB
  __shared__ short Bs[2][8][96][8];
  __shared__ float S[96][97];        // 37.2 KB scores (+pad)
  __shared__ float C1[85][12];
  __shared__ float M1[85][12];
  const int b = blockIdx.x;
  const int tid = threadIdx.x, wave = tid >> 6, lane = tid & 63;
  const int RPB = (STAGE == 1) ? 96 : 85;
  const long base = (long)b * RPB * 2048;
  const int wr0 = (wave >> 1) * 48, wc0 = (wave & 1) * 48;
  const int fr = lane & 15, fk = lane >> 4;

  f32x4 acc[3][3];
  const f32x4 zz = {0.f, 0.f, 0.f, 0.f};
#pragma unroll
  for (int i = 0; i < 3; ++i)
#pragma unroll
    for (int j = 0; j < 3; ++j) acc[i][j] = zz;

  auto stage = [&](int bb, int kb) {
#pragma unroll
    for (int it = 0; it < 3; ++it) {
      const int u = it * 256 + tid;  // uniform base + lane*16
      const int row = u % 96, kg = u / 96;
      gload_lds16(Aq + base + (long)row * 2048 + kb + kg * 8, (char*)As[bb] + u * 16);
      gload_lds16(Bk + base + (long)row * 2048 + kb + kg * 8, (char*)Bs[bb] + u * 16);
    }
  };

  stage(0, 0);
  __syncthreads();
  for (int kt = 0; kt < 32; ++kt) {
    const int cur = kt & 1;
    if (kt < 31) stage(cur ^ 1, (kt + 1) * 64);
#pragma unroll
    for (int ks = 0; ks < 2; ++ks) {
      const int kgx = ks * 4 + fk;
      s16x8 af[3], bv[3];
#pragma unroll
      for (int i = 0; i < 3; ++i) {
        af[i] = *(const s16x8*)&As[cur][kgx][wr0 + i * 16 + fr][0];
        bv[i] = *(const s16x8*)&Bs[cur][kgx][wc0 + i * 16 + fr][0];
      }
#pragma unroll
      for (int i = 0; i < 3; ++i)
#pragma unroll
        for (int j = 0; j < 3; ++j)
          acc[i][j] = __builtin_amdgcn_mfma_f32_16x16x32_bf16(af[i], bv[j], acc[i][j], 0, 0, 0);
    }
    __syncthreads();
  }
  // scores -> LDS  (C/D layout: col=lane&15, row=(lane>>4)*4+reg)
#pragma unroll
  for (int i = 0; i < 3; ++i)
#pragma unroll
    for (int j = 0; j < 3; ++j)
#pragma unroll
      for (int r = 0; r < 4; ++r)
        S[wr0 + i * 16 + fk * 4 + r][wc0 + j * 16 + fr] = acc[i][j][r];
  __syncthreads();

  if (STAGE == 2) {
    if (tid < 85) {
      float mx = -1e30f;
      for (int u = 0; u < 85; ++u) mx = fmaxf(mx, S[tid][u]);
      float sum = 0.f;
      for (int u = 0; u < 85; ++u) {
        const float e = expf((S[tid][u] - mx) * SCALE_F);
        S[tid][u] = e;
        sum += e;
      }
      (&C1[0][0])[tid] = wm[tid] / sum;
    }
    __syncthreads();
    if (tid < 85) {
      float a = 0.f;
      for (int i = 0; i < 85; ++i) a += (&C1[0][0])[i] * S[i][tid];
      outp[b * 85 + tid] = a;
    }
  } else {
    for (int p = tid; p < 85 * 12; p += 256) {
      const int w = p / 12, n = p % 12;
      const int row = w + n;
      float mx = -1e30f;
      for (int m = 0; m < 12; ++m) mx = fmaxf(mx, S[row][w + m]);
      float sum = 0.f;
      for (int m = 0; m < 12; ++m) sum += expf((S[row][w + m] - mx) * SCALE_F);
      M1[w][n] = mx;
      C1[w][n] = wm[n] / sum;
    }
    __syncthreads();
    for (int p = tid; p < 85 * 12; p += 256) {
      const int w = p / 12, m = p % 12;
      float a = 0.f;
#pragma unroll
      for (int n = 0; n < 12; ++n)
        a += C1[w][n] * expf((S[w + n][w + m] - M1[w][n]) * SCALE_F);
      outp[(b * 85 + w) * 12 + m] = a;
    }
  }
}

// ---------------- x = ds_w-downsample (fp32 fc) + nsa_feats, fp32 out --------
__global__ __launch_bounds__(256) void combine_kernel(const float* fc32, const short* vp,
                                                      const float* p1, const float* dsw_g,
                                                      const float* dsb, float* X) {
  const int b = blockIdx.y, d0 = blockIdx.x * 128;
  const int t = threadIdx.x;
  __shared__ float fcs[96][128];
  __shared__ short vps[96][128];
  __shared__ float dsw[85][96];
  __shared__ float p1s[85][12];
  for (int s = t; s < 96 * 32; s += 256) {
    const int row = s >> 5, c4 = (s & 31) * 4;
    *(float4*)&fcs[row][c4] = *(const float4*)(fc32 + ((long)b * 96 + row) * 2048 + d0 + c4);
  }
  for (int s = t; s < 96 * 16; s += 256) {
    const int row = s >> 4, c8 = (s & 15) * 8;
    *(s16x8*)&vps[row][c8] = *(const s16x8*)(vp + ((long)b * 96 + row) * 2048 + d0 + c8);
  }
  for (int s = t; s < 85 * 96; s += 256) (&dsw[0][0])[s] = dsw_g[s];
  for (int s = t; s < 85 * 12; s += 256) (&p1s[0][0])[s] = p1[(long)b * 85 * 12 + s];
  __syncthreads();
  const int dp = (t & 63) * 2, wslot = t >> 6;
  for (int w = wslot; w < 85; w += 4) {
    float a0 = dsb[w], a1 = a0;
    for (int p = 0; p < 96; ++p) {
      const float c = dsw[w][p];
      a0 += c * fcs[p][dp];
      a1 += c * fcs[p][dp + 1];
    }
#pragma unroll
    for (int m = 0; m < 12; ++m) {
      const unsigned vv = *(const unsigned*)&vps[w + m][dp];
      const float c = p1s[w][m];
      a0 += c * __uint_as_float(vv << 16);
      a1 += c * __uint_as_float(vv & 0xffff0000u);
    }
    const long o = ((long)b * 85 + w) * 2048 + d0 + dp;
    X[o] = a0;
    X[o + 1] = a1;
  }
}

// ---------------- LayerNorm over D: fp32 in, bf16 out ----------------
__global__ __launch_bounds__(256) void ln_kernel(const float* X, const float* gam,
                                                 const float* bet, short* XLN) {
  const long row = blockIdx.x;
  const int t = threadIdx.x;
  float v[8];
  *(float4*)&v[0] = *(const float4*)(X + row * 2048 + t * 8);
  *(float4*)&v[4] = *(const float4*)(X + row * 2048 + t * 8 + 4);
  float s = 0.f, q = 0.f;
#pragma unroll
  for (int e = 0; e < 8; ++e) { s += v[e]; q += v[e] * v[e]; }
#pragma unroll
  for (int o = 32; o > 0; o >>= 1) { s += __shfl_down(s, o); q += __shfl_down(q, o); }
  __shared__ float rs[4], rq[4];
  if ((t & 63) == 0) { rs[t >> 6] = s; rq[t >> 6] = q; }
  __syncthreads();
  const float S = rs[0] + rs[1] + rs[2] + rs[3];
  const float Q = rq[0] + rq[1] + rq[2] + rq[3];
  const float mu = S * (1.f / 2048.f);
  const float var = Q * (1.f / 2048.f) - mu * mu;
  const float rstd = rsqrtf(var + LN_EPS_F);
  s16x8 o8;
#pragma unroll
  for (int e = 0; e < 8; ++e) {
    const int c = t * 8 + e;
    o8[e] = f2b((v[e] - mu) * rstd * gam[c] + bet[c]);
  }
  *(s16x8*)(XLN + row * 2048 + t * 8) = o8;
}

// ---------------- z2[b,d] = sum_u p2[b,u] * xln[b,u,d]  (bf16, 64 rows) ------
__global__ __launch_bounds__(256) void z2_kernel(const short* xln, const float* p2, short* z2) {
  const int b = blockIdx.y, d = blockIdx.x * 256 + threadIdx.x;
  __shared__ float pc[85];
  if (threadIdx.x < 85) pc[threadIdx.x] = p2[b * 85 + threadIdx.x];
  __syncthreads();
  float a = 0.f;
  for (int u = 0; u < 85; ++u) a += pc[u] * b2f(xln[((long)b * 85 + u) * 2048 + d]);
  z2[(long)b * 2048 + d] = f2b(a);
}

extern "C" void kernel_launch(void* const* d_in, const int* in_sizes, int n_in,
                              void* d_out, int out_size, void* d_ws, size_t ws_size,
                              hipStream_t stream) {
  char* ws = (char*)d_ws;
  size_t off = 0;
  auto alloc = [&](size_t bytes) -> char* {
    char* p = ws + off;
    off += (bytes + 255) & ~(size_t)255;
    return p;
  };

  short* A1   = (short*)alloc((size_t)M1_ * D_ * 2);   // 24 MB
  short* WqT1 = (short*)alloc((size_t)D_ * D_ * 2);
  short* WkT1 = (short*)alloc((size_t)D_ * D_ * 2);
  short* WqT2 = (short*)alloc((size_t)D_ * D_ * 2);
  short* WkT2 = (short*)alloc((size_t)D_ * D_ * 2);
  short* Gt1  = (short*)alloc((size_t)D_ * D_ * 2);
  short* Gt2  = (short*)alloc((size_t)D_ * D_ * 2);
  short* Wv1c = (short*)alloc((size_t)D_ * D_ * 2);
  short* Wv2c = (short*)alloc((size_t)D_ * D_ * 2);
  short* Y1   = (short*)alloc((size_t)M1_ * D_ * 2);   // 24 MB
  short* VP   = (short*)alloc((size_t)M1_ * D_ * 2);   // 24 MB
  float* X    = (float*)alloc((size_t)M2_ * D_ * 4);   // 44.6 MB
  float* P1   = (float*)alloc((size_t)B_ * W_ * N_ * 4);
  short* Z2   = (short*)alloc((size_t)64 * D_ * 2);
  float* P2   = (float*)alloc((size_t)B_ * W_ * 4);
  float* WM   = (float*)alloc(512);
  float* R1   = (float*)alloc(D_ * 4);
  float* R2   = (float*)alloc(D_ * 4);

  short* XLN = A1;  // 5504*2048*2 = 22.5 MB <= A1 (24 MB)
  short* Y2  = Y1;  // 5504 rows <= Y1 (6144 rows)

  if (off > ws_size) return;

  // zero P2..R2 (contiguous) + d_out (atomic target)
  const size_t zbytes = (size_t)((char*)R2 - (char*)P2) + D_ * 4;
  hipMemsetAsync(P2, 0, zbytes, stream);
  hipMemsetAsync(d_out, 0, (size_t)B_ * D_ * 4, stream);

  // --- weight prep ---
  castA_kernel<<<dim3(6144), 256, 0, stream>>>((const float*)d_in[0], A1, M1_ * D_);
  Cast4T ct;
  ct.s[0] = (const float*)d_in[1];  ct.d[0] = WqT1;
  ct.s[1] = (const float*)d_in[3];  ct.d[1] = WkT1;
  ct.s[2] = (const float*)d_in[13]; ct.d[2] = WqT2;
  ct.s[3] = (const float*)d_in[15]; ct.d[3] = WkT2;
  castT_kernel<<<dim3(32, 32, 4), 256, 0, stream>>>(ct);
  Cast2 cv;
  cv.s[0] = (const float*)d_in[5];  cv.d[0] = Wv1c;
  cv.s[1] = (const float*)d_in[17]; cv.d[1] = Wv2c;
  cast2_kernel<<<dim3(2048, 2), 256, 0, stream>>>(cv, D_ * D_);
  prep_kernel<<<dim3(129), 256, 0, stream>>>(
      (const float*)d_in[7], (const float*)d_in[8],
      (const float*)d_in[19], (const float*)d_in[20], WM,
      (const float*)d_in[3], (const float*)d_in[2], R1,
      (const float*)d_in[15], (const float*)d_in[14], R2);

  // Gt = (Wk^T) @ (Wq^T)^T
  GemmArgs gg;
  gg.A[0] = WkT1; gg.Wt[0] = WqT1; gg.bias[0] = nullptr; gg.C[0] = Gt1;
  gg.A[1] = WkT2; gg.Wt[1] = WqT2; gg.bias[1] = nullptr; gg.C[1] = Gt2;
  gg.mlim = 2048;
  gemm_nt_bf16<0><<<dim3(16, 16, 2), 256, 0, stream>>>(gg);

  // stage-1: VP = A1@Wv1^T + bv1 ; Y1 = A1@Gt1^T + r1
  GemmArgs g1;
  g1.A[0] = A1; g1.Wt[0] = Wv1c; g1.bias[0] = (const float*)d_in[6]; g1.C[0] = VP;
  g1.A[1] = A1; g1.Wt[1] = Gt1;  g1.bias[1] = R1;                    g1.C[1] = Y1;
  g1.mlim = M1_;
  gemm_nt_bf16<0><<<dim3(48, 16, 2), 256, 0, stream>>>(g1);

  attn_mfma_kernel<1><<<dim3(64), 256, 0, stream>>>(Y1, A1, WM, P1);

  combine_kernel<<<dim3(16, 64), 256, 0, stream>>>((const float*)d_in[0], VP, P1,
                                                   (const float*)d_in[9],
                                                   (const float*)d_in[10], X);
  ln_kernel<<<dim3(5440), 256, 0, stream>>>(X, (const float*)d_in[11], (const float*)d_in[12], XLN);

  // stage-2: Y2 = XLN@Gt2^T + r2
  GemmArgs g2;
  g2.A[0] = XLN; g2.Wt[0] = Gt2; g2.bias[0] = R2; g2.C[0] = Y2;
  g2.mlim = M2P_;
  gemm_nt_bf16<0><<<dim3(43, 16, 1), 256, 0, stream>>>(g2);

  attn_mfma_kernel<2><<<dim3(64), 256, 0, stream>>>(Y2, XLN, WM + 16, P2);

  z2_kernel<<<dim3(8, 64), 256, 0, stream>>>(XLN, P2, Z2);

  // out = sum over 4 K-slices of Z2 @ Wv2^T (+ bias on slice 0), atomic fp32
  out_gemm_kernel<<<dim3(4, 16), 256, 0, stream>>>(Z2, Wv2c, (const float*)d_in[18],
                                                   (float*)d_out);
}

// Round 9
// 815.124 us; speedup vs baseline: 1.5357x; 1.0325x over previous
//
#include <hip/hip_runtime.h>
#include <hip/hip_bf16.h>

#define DEV __device__ __forceinline__

typedef __attribute__((ext_vector_type(8))) short s16x8;
typedef __attribute__((ext_vector_type(4))) float f32x4;

#define B_ 64
#define P_ 96
#define N_ 12
#define D_ 2048
#define W_ 85
#define M1_ (B_ * P_)   // 6144 rows stage-1
#define M2_ (B_ * W_)   // 5440 rows stage-2
#define M2P_ 5504       // padded to 43*128
#define SCALE_F 0.02209708691207961f
#define LN_EPS_F 1e-5f

DEV float b2f(short h) { return __uint_as_float(((unsigned)(unsigned short)h) << 16); }
DEV short f2b(float f) {
  __hip_bfloat16 h = __float2bfloat16(f);
  return *reinterpret_cast<short*>(&h);
}

// async global->LDS, 16B per lane. LDS dest is wave-uniform base + lane*16.
DEV void gload_lds16(const void* g, void* l) {
  __builtin_amdgcn_global_load_lds(
      (const __attribute__((address_space(1))) unsigned int*)(unsigned long long)g,
      (__attribute__((address_space(3))) unsigned int*)(unsigned int)(unsigned long long)l,
      16, 0, 0);
}

// ---------------- fp32 -> bf16 casts ----------------
__global__ __launch_bounds__(256) void castA_kernel(const float* s, short* d, int n) {
  const int i = (blockIdx.x * 256 + threadIdx.x) * 8;
  if (i >= n) return;
  float4 a = *(const float4*)(s + i);
  float4 b = *(const float4*)(s + i + 4);
  s16x8 o;
  o[0] = f2b(a.x); o[1] = f2b(a.y); o[2] = f2b(a.z); o[3] = f2b(a.w);
  o[4] = f2b(b.x); o[5] = f2b(b.y); o[6] = f2b(b.z); o[7] = f2b(b.w);
  *(s16x8*)(d + i) = o;
}

struct Cast2 { const float* s[2]; short* d[2]; };

__global__ __launch_bounds__(256) void cast2_kernel(Cast2 j, int n) {
  const int jb = blockIdx.y;
  const int i = (blockIdx.x * 256 + threadIdx.x) * 8;
  if (i >= n) return;
  const float* src = j.s[jb] + i;
  float4 a = *(const float4*)(src);
  float4 b = *(const float4*)(src + 4);
  s16x8 o;
  o[0] = f2b(a.x); o[1] = f2b(a.y); o[2] = f2b(a.z); o[3] = f2b(a.w);
  o[4] = f2b(b.x); o[5] = f2b(b.y); o[6] = f2b(b.z); o[7] = f2b(b.w);
  *(s16x8*)(j.d[jb] + i) = o;
}

// ---------------- fp32 -> bf16 transposing cast: WT[d][e] = W[e][d] ----------
struct Cast4T { const float* s[4]; short* d[4]; };

__global__ __launch_bounds__(256) void castT_kernel(Cast4T j) {
  __shared__ float tl[64][65];  // [d][e], padded
  const int z = blockIdx.z;
  const float* src = j.s[z];
  short* dst = j.d[z];
  const int e0 = blockIdx.x * 64, d0 = blockIdx.y * 64;
  const int t = threadIdx.x;
  for (int i = t; i < 64 * 16; i += 256) {
    const int er = i >> 4, c4 = (i & 15) * 4;
    const float4 v = *(const float4*)(src + (long)(e0 + er) * 2048 + d0 + c4);
    tl[c4 + 0][er] = v.x;
    tl[c4 + 1][er] = v.y;
    tl[c4 + 2][er] = v.z;
    tl[c4 + 3][er] = v.w;
  }
  __syncthreads();
  for (int i = t; i < 64 * 8; i += 256) {
    const int dr = i >> 3, e8 = (i & 7) * 8;
    s16x8 o;
#pragma unroll
    for (int e = 0; e < 8; ++e) o[e] = f2b(tl[dr][e8 + e]);
    *(s16x8*)(dst + (long)(d0 + dr) * 2048 + e0 + e8) = o;
  }
}

// ---------------- prep: constant softmax masks + q-bias fold vectors --------
__global__ __launch_bounds__(256) void prep_kernel(const float* nw, const float* nb,
                                                   const float* sw, const float* sb, float* wm,
                                                   const float* wk1, const float* bq1, float* r1,
                                                   const float* wk2, const float* bq2, float* r2) {
  const int bx = blockIdx.x, t = threadIdx.x;
  if (bx == 0) {
    __shared__ float l1[12], l2[85];
    if (t < 12) { float s = nb[t]; for (int n = 0; n < 12; ++n) s += nw[t * 12 + n]; l1[t] = s; }
    if (t < 85) { float s = sb[t]; for (int w = 0; w < 85; ++w) s += sw[t * 85 + w]; l2[t] = s; }
    __syncthreads();
    if (t == 0) {
      float m = l1[0]; for (int i = 1; i < 12; ++i) m = fmaxf(m, l1[i]);
      float s = 0.f; float e[12];
      for (int i = 0; i < 12; ++i) { e[i] = expf(l1[i] - m); s += e[i]; }
      for (int i = 0; i < 12; ++i) wm[i] = e[i] / s;
    } else if (t == 64) {
      float m = l2[0]; for (int i = 1; i < 85; ++i) m = fmaxf(m, l2[i]);
      float s = 0.f;
      for (int i = 0; i < 85; ++i) s += expf(l2[i] - m);
      for (int i = 0; i < 85; ++i) wm[16 + i] = expf(l2[i] - m) / s;
    }
    return;
  }
  const int idx = bx - 1;
  const int stage = idx >> 6;
  const int ec = (idx & 63) >> 3, dpc = idx & 7;
  const float* wk = stage ? wk2 : wk1;
  const float* bq = stage ? bq2 : bq1;
  float* r = stage ? r2 : r1;
  const int dp = dpc * 256 + t;
  const int e0 = ec * 256;
  float s = 0.f;
  for (int e = e0; e < e0 + 256; ++e) s += bq[e] * wk[(long)e * 2048 + dp];
  atomicAdd(&r[dp], s);
}

// ---------------- bf16 MFMA GEMM: C[.,2048] = A @ W^T (+ col bias) ----------
// T4 counted-vmcnt schedule: dbuf LDS; loads stay in flight ACROSS barriers.
// Per K-step: vmcnt(4) [not 0] -> s_barrier -> ds_read frags -> lgkmcnt(0) ->
// s_barrier -> stage kt+2 into just-read buffer -> 16 MFMA (overlap new loads).
struct GemmArgs {
  const short* A[3];
  const short* Wt[3];
  const float* bias[3];
  void* C[3];
  int mlim;
};

template <int OM>
__global__ __launch_bounds__(256) void gemm_nt_bf16(GemmArgs g) {
  __shared__ short As[2][4096];  // 2 x 8 KB  [buf][kg][row][8bf16]
  __shared__ short Bs[2][4096];
  const int z = blockIdx.z;
  const short* A = g.A[z];
  const short* Wm = g.Wt[z];
  const int tid = threadIdx.x, wave = tid >> 6, lane = tid & 63;
  const int wmo = (wave >> 1) * 64, wno = (wave & 1) * 64;
  const long rowA0 = (long)blockIdx.x * 128;
  const long rowB0 = (long)blockIdx.y * 128;
  const int kg = lane >> 4, rsub = lane & 15;

  // hoisted per-thread source pointers (stage row = {lane, 64+lane}, col = wave*8)
  const short* pA0 = A + (rowA0 + lane) * 2048 + wave * 8;
  const short* pA1 = pA0 + 64 * 2048;
  const short* pB0 = Wm + (rowB0 + lane) * 2048 + wave * 8;
  const short* pB1 = pB0 + 64 * 2048;

  f32x4 acc[4][4];
  const f32x4 zz = {0.f, 0.f, 0.f, 0.f};
#pragma unroll
  for (int i = 0; i < 4; ++i)
#pragma unroll
    for (int jj = 0; jj < 4; ++jj) acc[i][jj] = zz;

  auto stage = [&](int bb, int kt2) {
    const int kb = kt2 * 32;  // elements
    gload_lds16(pA0 + kb, (char*)As[bb] + (wave * 128) * 16);
    gload_lds16(pA1 + kb, (char*)As[bb] + (wave * 128 + 64) * 16);
    gload_lds16(pB0 + kb, (char*)Bs[bb] + (wave * 128) * 16);
    gload_lds16(pB1 + kb, (char*)Bs[bb] + (wave * 128 + 64) * 16);
  };

  stage(0, 0);
  stage(1, 1);  // 8 loads/thread in flight
  for (int kt = 0; kt < 64; ++kt) {
    const int cur = kt & 1;
    if (kt < 63) {
      asm volatile("s_waitcnt vmcnt(4)" ::: "memory");  // cur's 4 done; next 4 fly
    } else {
      asm volatile("s_waitcnt vmcnt(0)" ::: "memory");  // final tile
    }
    __builtin_amdgcn_s_barrier();  // all threads' cur loads landed
    s16x8 af[4], bv[4];
#pragma unroll
    for (int f = 0; f < 4; ++f) {
      af[f] = *(const s16x8*)(As[cur] + (kg * 128 + wmo + f * 16 + rsub) * 8);
      bv[f] = *(const s16x8*)(Bs[cur] + (kg * 128 + wno + f * 16 + rsub) * 8);
    }
    asm volatile("s_waitcnt lgkmcnt(0)" ::: "memory");  // my reads retired
    __builtin_amdgcn_sched_barrier(0);
    __builtin_amdgcn_s_barrier();  // all waves' reads done -> safe to overwrite
    if (kt < 62) stage(cur, kt + 2);  // refill just-read buffer; flies over MFMAs
#pragma unroll
    for (int i = 0; i < 4; ++i)
#pragma unroll
      for (int jj = 0; jj < 4; ++jj)
        acc[i][jj] = __builtin_amdgcn_mfma_f32_16x16x32_bf16(af[i], bv[jj], acc[i][jj], 0, 0, 0);
  }

  const float* bias = g.bias[z];
#pragma unroll
  for (int i = 0; i < 4; ++i) {
    const long row = rowA0 + wmo + i * 16 + (lane >> 4) * 4;
#pragma unroll
    for (int jj = 0; jj < 4; ++jj) {
      const long col = rowB0 + wno + jj * 16 + (lane & 15);
      const float bvl = bias ? bias[col] : 0.f;
#pragma unroll
      for (int r = 0; r < 4; ++r) {
        if (row + r < g.mlim) {
          if (OM == 0)
            ((short*)g.C[z])[(row + r) * 2048 + col] = f2b(acc[i][jj][r] + bvl);
          else
            ((float*)g.C[z])[(row + r) * 2048 + col] = acc[i][jj][r] + bvl;
        }
      }
    }
  }
}

// ---------------- out = Z2 @ Wv2^T + bv2, K-split, atomic fp32 epilogue -----
__global__ __launch_bounds__(256) void out_gemm_kernel(const short* A, const short* Wm,
                                                       const float* bias, float* C) {
  __shared__ short As[2][4][64][8];   // 2 x 4 KB
  __shared__ short Bs[2][4][128][8];  // 2 x 8 KB
  const int kz = blockIdx.x;  // K-slice
  const long rowB0 = (long)blockIdx.y * 128;
  const int tid = threadIdx.x, wave = tid >> 6, lane = tid & 63;
  const int wno = wave * 32;
  const int kgx = lane >> 4, rsub = lane & 15;

  f32x4 acc[4][2];
  const f32x4 zz = {0.f, 0.f, 0.f, 0.f};
#pragma unroll
  for (int f = 0; f < 4; ++f) { acc[f][0] = zz; acc[f][1] = zz; }

  auto stage = [&](int bb, int kbase) {
    gload_lds16(A + (long)lane * 2048 + kbase + wave * 8, (char*)As[bb] + tid * 16);
#pragma unroll
    for (int i = 0; i < 2; ++i) {
      const int row = i * 64 + lane;
      gload_lds16(Wm + (rowB0 + row) * 2048 + kbase + wave * 8,
                  (char*)Bs[bb] + (wave * 128 + i * 64) * 16);
    }
  };

  const int kb0 = kz * 512;
  stage(0, kb0);
  __syncthreads();
  for (int kt = 0; kt < 16; ++kt) {
    const int cur = kt & 1;
    if (kt < 15) stage(cur ^ 1, kb0 + (kt + 1) * 32);
    s16x8 af[4], bv[2];
#pragma unroll
    for (int f = 0; f < 4; ++f) af[f] = *(const s16x8*)&As[cur][kgx][f * 16 + rsub][0];
#pragma unroll
    for (int j = 0; j < 2; ++j) bv[j] = *(const s16x8*)&Bs[cur][kgx][wno + j * 16 + rsub][0];
#pragma unroll
    for (int f = 0; f < 4; ++f)
#pragma unroll
      for (int j = 0; j < 2; ++j)
        acc[f][j] = __builtin_amdgcn_mfma_f32_16x16x32_bf16(af[f], bv[j], acc[f][j], 0, 0, 0);
    __syncthreads();
  }

#pragma unroll
  for (int f = 0; f < 4; ++f) {
    const int row = f * 16 + (lane >> 4) * 4;
#pragma unroll
    for (int j = 0; j < 2; ++j) {
      const long col = rowB0 + wno + j * 16 + (lane & 15);
      const float bvl = (kz == 0) ? bias[col] : 0.f;
#pragma unroll
      for (int r = 0; r < 4; ++r)
        atomicAdd(&C[(long)(row + r) * 2048 + col], acc[f][j][r] + bvl);
    }
  }
}

// ---------------- batched MFMA attention scores + fused wmask softmax -------
template <int STAGE>
__global__ __launch_bounds__(256) void attn_mfma_kernel(const short* Aq, const short* Bk,
                                                        const float* wm, float* outp) {
  __shared__ short As[2][8][96][8];  // 2 x 12 KB
  __shared__ short Bs[2][8][96][8];
  __shared__ float S[96][97];        // 37.2 KB scores (+pad)
  __shared__ float C1[85][12];
  __shared__ float M1[85][12];
  const int b = blockIdx.x;
  const int tid = threadIdx.x, wave = tid >> 6, lane = tid & 63;
  const int RPB = (STAGE == 1) ? 96 : 85;
  const long base = (long)b * RPB * 2048;
  const int wr0 = (wave >> 1) * 48, wc0 = (wave & 1) * 48;
  const int fr = lane & 15, fk = lane >> 4;

  f32x4 acc[3][3];
  const f32x4 zz = {0.f, 0.f, 0.f, 0.f};
#pragma unroll
  for (int i = 0; i < 3; ++i)
#pragma unroll
    for (int j = 0; j < 3; ++j) acc[i][j] = zz;

  auto stage = [&](int bb, int kb) {
#pragma unroll
    for (int it = 0; it < 3; ++it) {
      const int u = it * 256 + tid;  // uniform base + lane*16
      const int row = u % 96, kg = u / 96;
      gload_lds16(Aq + base + (long)row * 2048 + kb + kg * 8, (char*)As[bb] + u * 16);
      gload_lds16(Bk + base + (long)row * 2048 + kb + kg * 8, (char*)Bs[bb] + u * 16);
    }
  };

  stage(0, 0);
  __syncthreads();
  for (int kt = 0; kt < 32; ++kt) {
    const int cur = kt & 1;
    if (kt < 31) stage(cur ^ 1, (kt + 1) * 64);
#pragma unroll
    for (int ks = 0; ks < 2; ++ks) {
      const int kgx = ks * 4 + fk;
      s16x8 af[3], bv[3];
#pragma unroll
      for (int i = 0; i < 3; ++i) {
        af[i] = *(const s16x8*)&As[cur][kgx][wr0 + i * 16 + fr][0];
        bv[i] = *(const s16x8*)&Bs[cur][kgx][wc0 + i * 16 + fr][0];
      }
#pragma unroll
      for (int i = 0; i < 3; ++i)
#pragma unroll
        for (int j = 0; j < 3; ++j)
          acc[i][j] = __builtin_amdgcn_mfma_f32_16x16x32_bf16(af[i], bv[j], acc[i][j], 0, 0, 0);
    }
    __syncthreads();
  }
  // scores -> LDS  (C/D layout: col=lane&15, row=(lane>>4)*4+reg)
#pragma unroll
  for (int i = 0; i < 3; ++i)
#pragma unroll
    for (int j = 0; j < 3; ++j)
#pragma unroll
      for (int r = 0; r < 4; ++r)
        S[wr0 + i * 16 + fk * 4 + r][wc0 + j * 16 + fr] = acc[i][j][r];
  __syncthreads();

  if (STAGE == 2) {
    if (tid < 85) {
      float mx = -1e30f;
      for (int u = 0; u < 85; ++u) mx = fmaxf(mx, S[tid][u]);
      float sum = 0.f;
      for (int u = 0; u < 85; ++u) {
        const float e = expf((S[tid][u] - mx) * SCALE_F);
        S[tid][u] = e;
        sum += e;
      }
      (&C1[0][0])[tid] = wm[tid] / sum;
    }
    __syncthreads();
    if (tid < 85) {
      float a = 0.f;
      for (int i = 0; i < 85; ++i) a += (&C1[0][0])[i] * S[i][tid];
      outp[b * 85 + tid] = a;
    }
  } else {
    for (int p = tid; p < 85 * 12; p += 256) {
      const int w = p / 12, n = p % 12;
      const int row = w + n;
      float mx = -1e30f;
      for (int m = 0; m < 12; ++m) mx = fmaxf(mx, S[row][w + m]);
      float sum = 0.f;
      for (int m = 0; m < 12; ++m) sum += expf((S[row][w + m] - mx) * SCALE_F);
      M1[w][n] = mx;
      C1[w][n] = wm[n] / sum;
    }
    __syncthreads();
    for (int p = tid; p < 85 * 12; p += 256) {
      const int w = p / 12, m = p % 12;
      float a = 0.f;
#pragma unroll
      for (int n = 0; n < 12; ++n)
        a += C1[w][n] * expf((S[w + n][w + m] - M1[w][n]) * SCALE_F);
      outp[(b * 85 + w) * 12 + m] = a;
    }
  }
}

// ---------------- x = ds_w-downsample (fp32 fc) + nsa_feats, fp32 out --------
__global__ __launch_bounds__(256) void combine_kernel(const float* fc32, const short* vp,
                                                      const float* p1, const float* dsw_g,
                                                      const float* dsb, float* X) {
  const int b = blockIdx.y, d0 = blockIdx.x * 128;
  const int t = threadIdx.x;
  __shared__ float fcs[96][128];
  __shared__ short vps[96][128];
  __shared__ float dsw[85][96];
  __shared__ float p1s[85][12];
  for (int s = t; s < 96 * 32; s += 256) {
    const int row = s >> 5, c4 = (s & 31) * 4;
    *(float4*)&fcs[row][c4] = *(const float4*)(fc32 + ((long)b * 96 + row) * 2048 + d0 + c4);
  }
  for (int s = t; s < 96 * 16; s += 256) {
    const int row = s >> 4, c8 = (s & 15) * 8;
    *(s16x8*)&vps[row][c8] = *(const s16x8*)(vp + ((long)b * 96 + row) * 2048 + d0 + c8);
  }
  for (int s = t; s < 85 * 96; s += 256) (&dsw[0][0])[s] = dsw_g[s];
  for (int s = t; s < 85 * 12; s += 256) (&p1s[0][0])[s] = p1[(long)b * 85 * 12 + s];
  __syncthreads();
  const int dp = (t & 63) * 2, wslot = t >> 6;
  for (int w = wslot; w < 85; w += 4) {
    float a0 = dsb[w], a1 = a0;
    for (int p = 0; p < 96; ++p) {
      const float c = dsw[w][p];
      a0 += c * fcs[p][dp];
      a1 += c * fcs[p][dp + 1];
    }
#pragma unroll
    for (int m = 0; m < 12; ++m) {
      const unsigned vv = *(const unsigned*)&vps[w + m][dp];
      const float c = p1s[w][m];
      a0 += c * __uint_as_float(vv << 16);
      a1 += c * __uint_as_float(vv & 0xffff0000u);
    }
    const long o = ((long)b * 85 + w) * 2048 + d0 + dp;
    X[o] = a0;
    X[o + 1] = a1;
  }
}

// ---------------- LayerNorm over D: fp32 in, bf16 out ----------------
__global__ __launch_bounds__(256) void ln_kernel(const float* X, const float* gam,
                                                 const float* bet, short* XLN) {
  const long row = blockIdx.x;
  const int t = threadIdx.x;
  float v[8];
  *(float4*)&v[0] = *(const float4*)(X + row * 2048 + t * 8);
  *(float4*)&v[4] = *(const float4*)(X + row * 2048 + t * 8 + 4);
  float s = 0.f, q = 0.f;
#pragma unroll
  for (int e = 0; e < 8; ++e) { s += v[e]; q += v[e] * v[e]; }
#pragma unroll
  for (int o = 32; o > 0; o >>= 1) { s += __shfl_down(s, o); q += __shfl_down(q, o); }
  __shared__ float rs[4], rq[4];
  if ((t & 63) == 0) { rs[t >> 6] = s; rq[t >> 6] = q; }
  __syncthreads();
  const float S = rs[0] + rs[1] + rs[2] + rs[3];
  const float Q = rq[0] + rq[1] + rq[2] + rq[3];
  const float mu = S * (1.f / 2048.f);
  const float var = Q * (1.f / 2048.f) - mu * mu;
  const float rstd = rsqrtf(var + LN_EPS_F);
  s16x8 o8;
#pragma unroll
  for (int e = 0; e < 8; ++e) {
    const int c = t * 8 + e;
    o8[e] = f2b((v[e] - mu) * rstd * gam[c] + bet[c]);
  }
  *(s16x8*)(XLN + row * 2048 + t * 8) = o8;
}

// ---------------- z2[b,d] = sum_u p2[b,u] * xln[b,u,d]  (bf16, 64 rows) ------
__global__ __launch_bounds__(256) void z2_kernel(const short* xln, const float* p2, short* z2) {
  const int b = blockIdx.y, d = blockIdx.x * 256 + threadIdx.x;
  __shared__ float pc[85];
  if (threadIdx.x < 85) pc[threadIdx.x] = p2[b * 85 + threadIdx.x];
  __syncthreads();
  float a = 0.f;
  for (int u = 0; u < 85; ++u) a += pc[u] * b2f(xln[((long)b * 85 + u) * 2048 + d]);
  z2[(long)b * 2048 + d] = f2b(a);
}

extern "C" void kernel_launch(void* const* d_in, const int* in_sizes, int n_in,
                              void* d_out, int out_size, void* d_ws, size_t ws_size,
                              hipStream_t stream) {
  char* ws = (char*)d_ws;
  size_t off = 0;
  auto alloc = [&](size_t bytes) -> char* {
    char* p = ws + off;
    off += (bytes + 255) & ~(size_t)255;
    return p;
  };

  short* A1   = (short*)alloc((size_t)M1_ * D_ * 2);   // 24 MB
  short* WqT1 = (short*)alloc((size_t)D_ * D_ * 2);
  short* WkT1 = (short*)alloc((size_t)D_ * D_ * 2);
  short* WqT2 = (short*)alloc((size_t)D_ * D_ * 2);
  short* WkT2 = (short*)alloc((size_t)D_ * D_ * 2);
  short* Gt1  = (short*)alloc((size_t)D_ * D_ * 2);
  short* Gt2  = (short*)alloc((size_t)D_ * D_ * 2);
  short* Wv1c = (short*)alloc((size_t)D_ * D_ * 2);
  short* Wv2c = (short*)alloc((size_t)D_ * D_ * 2);
  short* Y1   = (short*)alloc((size_t)M1_ * D_ * 2);   // 24 MB
  short* VP   = (short*)alloc((size_t)M1_ * D_ * 2);   // 24 MB
  float* X    = (float*)alloc((size_t)M2_ * D_ * 4);   // 44.6 MB
  float* P1   = (float*)alloc((size_t)B_ * W_ * N_ * 4);
  short* Z2   = (short*)alloc((size_t)64 * D_ * 2);
  float* P2   = (float*)alloc((size_t)B_ * W_ * 4);
  float* WM   = (float*)alloc(512);
  float* R1   = (float*)alloc(D_ * 4);
  float* R2   = (float*)alloc(D_ * 4);

  short* XLN = A1;  // 5504*2048*2 = 22.5 MB <= A1 (24 MB)
  short* Y2  = Y1;  // 5504 rows <= Y1 (6144 rows)

  if (off > ws_size) return;

  // zero P2..R2 (contiguous) + d_out (atomic target)
  const size_t zbytes = (size_t)((char*)R2 - (char*)P2) + D_ * 4;
  hipMemsetAsync(P2, 0, zbytes, stream);
  hipMemsetAsync(d_out, 0, (size_t)B_ * D_ * 4, stream);

  // --- weight prep ---
  castA_kernel<<<dim3(6144), 256, 0, stream>>>((const float*)d_in[0], A1, M1_ * D_);
  Cast4T ct;
  ct.s[0] = (const float*)d_in[1];  ct.d[0] = WqT1;
  ct.s[1] = (const float*)d_in[3];  ct.d[1] = WkT1;
  ct.s[2] = (const float*)d_in[13]; ct.d[2] = WqT2;
  ct.s[3] = (const float*)d_in[15]; ct.d[3] = WkT2;
  castT_kernel<<<dim3(32, 32, 4), 256, 0, stream>>>(ct);
  Cast2 cv;
  cv.s[0] = (const float*)d_in[5];  cv.d[0] = Wv1c;
  cv.s[1] = (const float*)d_in[17]; cv.d[1] = Wv2c;
  cast2_kernel<<<dim3(2048, 2), 256, 0, stream>>>(cv, D_ * D_);
  prep_kernel<<<dim3(129), 256, 0, stream>>>(
      (const float*)d_in[7], (const float*)d_in[8],
      (const float*)d_in[19], (const float*)d_in[20], WM,
      (const float*)d_in[3], (const float*)d_in[2], R1,
      (const float*)d_in[15], (const float*)d_in[14], R2);

  // Gt = (Wk^T) @ (Wq^T)^T
  GemmArgs gg;
  gg.A[0] = WkT1; gg.Wt[0] = WqT1; gg.bias[0] = nullptr; gg.C[0] = Gt1;
  gg.A[1] = WkT2; gg.Wt[1] = WqT2; gg.bias[1] = nullptr; gg.C[1] = Gt2;
  gg.mlim = 2048;
  gemm_nt_bf16<0><<<dim3(16, 16, 2), 256, 0, stream>>>(gg);

  // stage-1: VP = A1@Wv1^T + bv1 ; Y1 = A1@Gt1^T + r1
  GemmArgs g1;
  g1.A[0] = A1; g1.Wt[0] = Wv1c; g1.bias[0] = (const float*)d_in[6]; g1.C[0] = VP;
  g1.A[1] = A1; g1.Wt[1] = Gt1;  g1.bias[1] = R1;                    g1.C[1] = Y1;
  g1.mlim = M1_;
  gemm_nt_bf16<0><<<dim3(48, 16, 2), 256, 0, stream>>>(g1);

  attn_mfma_kernel<1><<<dim3(64), 256, 0, stream>>>(Y1, A1, WM, P1);

  combine_kernel<<<dim3(16, 64), 256, 0, stream>>>((const float*)d_in[0], VP, P1,
                                                   (const float*)d_in[9],
                                                   (const float*)d_in[10], X);
  ln_kernel<<<dim3(5440), 256, 0, stream>>>(X, (const float*)d_in[11], (const float*)d_in[12], XLN);

  // stage-2: Y2 = XLN@Gt2^T + r2
  GemmArgs g2;
  g2.A[0] = XLN; g2.Wt[0] = Gt2; g2.bias[0] = R2; g2.C[0] = Y2;
  g2.mlim = M2P_;
  gemm_nt_bf16<0><<<dim3(43, 16, 1), 256, 0, stream>>>(g2);

  attn_mfma_kernel<2><<<dim3(64), 256, 0, stream>>>(Y2, XLN, WM + 16, P2);

  z2_kernel<<<dim3(8, 64), 256, 0, stream>>>(XLN, P2, Z2);

  // out = sum over 4 K-slices of Z2 @ Wv2^T (+ bias on slice 0), atomic fp32
  out_gemm_kernel<<<dim3(4, 16), 256, 0, stream>>>(Z2, Wv2c, (const float*)d_in[18],
                                                   (float*)d_out);
}